// Round 1
// baseline (865.403 us; speedup 1.0000x reference)
//
#include <hip/hip_runtime.h>
#include <cstdint>
#include <cstddef>

// ---------------- constants ----------------
constexpr int T_SEQ = 4096;
constexpr int NH    = 16;
constexpr int HD    = 128;
constexpr int DIM   = 2048;
constexpr int HDIM  = 2048;   // NH*HD

typedef __attribute__((ext_vector_type(8))) short  short8;
typedef __attribute__((ext_vector_type(4))) float  f32x4;
typedef __attribute__((ext_vector_type(8))) unsigned short u16x8;
typedef __attribute__((ext_vector_type(4))) unsigned short u16x4;

__device__ __forceinline__ unsigned short f2bf(float f) {
  unsigned u = __float_as_uint(f);
  return (unsigned short)((u + 0x7FFFu + ((u >> 16) & 1u)) >> 16);  // RNE
}
__device__ __forceinline__ float bf2f(unsigned short h) {
  return __uint_as_float(((unsigned)h) << 16);
}
__device__ __forceinline__ void gload_lds16(const void* g, void* l) {
  __builtin_amdgcn_global_load_lds((const __attribute__((address_space(1))) void*)g,
                                   (__attribute__((address_space(3))) void*)l, 16, 0, 0);
}

// ---------------- fp32 -> bf16 convert ----------------
__global__ __launch_bounds__(256) void cvt_f32_bf16(const float* __restrict__ in,
                                                    unsigned short* __restrict__ out, int n4) {
  int i = blockIdx.x * 256 + threadIdx.x;
  if (i < n4) {
    float4 v = ((const float4*)in)[i];
    u16x4 o; o.x = f2bf(v.x); o.y = f2bf(v.y); o.z = f2bf(v.z); o.w = f2bf(v.w);
    ((u16x4*)out)[i] = o;
  }
}

// ---------------- RoPE tables ----------------
__global__ __launch_bounds__(256) void rope_tables(float* __restrict__ cosT, float* __restrict__ sinT) {
  int idx = blockIdx.x * 256 + threadIdx.x;           // T_SEQ*64
  if (idx >= T_SEQ * 64) return;
  int t = idx >> 6, i = idx & 63;
  float ang = (i < 32) ? exp2f(-10.0f * (float)i / 31.0f) : 0.0f;  // (1/1024)^(i/31)
  float th = (float)t * ang;
  cosT[idx] = cosf(th);
  sinT[idx] = sinf(th);
}

// ---------------- GEMM: C = A * B^T  (A:[M][K] bf16, B:[N][K] bf16) ----------------
// 128x128 tile, BK=64, 4 waves (2x2), 16x16x32 MFMA. MODE 0: write bf16 into qkv layout
// [c][h][t][d]; MODE 1: write fp32 [t][n].
template <int MODE>
__global__ __launch_bounds__(256) void gemm_bt(const unsigned short* __restrict__ A,
                                               const unsigned short* __restrict__ B,
                                               int K, unsigned short* __restrict__ outb,
                                               float* __restrict__ outf, int N) {
  __shared__ unsigned short As[128 * 64];
  __shared__ unsigned short Bs[128 * 64];
  const int tid = threadIdx.x;
  const int w = tid >> 6, lane = tid & 63;
  const int wm = w >> 1, wn = w & 1;
  const int m0 = blockIdx.x * 128, n0 = blockIdx.y * 128;
  const int lr = lane >> 4, lc = lane & 15;
  const int srow = lane >> 3, scol = (lane & 7) * 8;   // staging: 8 rows x 64 cols per 1KB chunk

  f32x4 acc[4][4] = {};
  const int nkt = K >> 6;
  for (int kt = 0; kt < nkt; kt++) {
    __syncthreads();
    const int k0 = kt * 64;
#pragma unroll
    for (int i = 0; i < 4; i++) {
      int row = (w * 4 + i) * 8 + srow;
      gload_lds16(A + (size_t)(m0 + row) * K + k0 + scol, (char*)As + (w * 4 + i) * 1024);
      gload_lds16(B + (size_t)(n0 + row) * K + k0 + scol, (char*)Bs + (w * 4 + i) * 1024);
    }
    __syncthreads();
#pragma unroll
    for (int kk = 0; kk < 2; kk++) {
      short8 a[4], b[4];
#pragma unroll
      for (int mi = 0; mi < 4; mi++)
        a[mi] = *(const short8*)(As + (wm * 64 + mi * 16 + lc) * 64 + kk * 32 + lr * 8);
#pragma unroll
      for (int ni = 0; ni < 4; ni++)
        b[ni] = *(const short8*)(Bs + (wn * 64 + ni * 16 + lc) * 64 + kk * 32 + lr * 8);
#pragma unroll
      for (int mi = 0; mi < 4; mi++)
#pragma unroll
        for (int ni = 0; ni < 4; ni++)
          acc[mi][ni] = __builtin_amdgcn_mfma_f32_16x16x32_bf16(a[mi], b[ni], acc[mi][ni], 0, 0, 0);
    }
  }
#pragma unroll
  for (int mi = 0; mi < 4; mi++)
#pragma unroll
    for (int ni = 0; ni < 4; ni++)
#pragma unroll
      for (int r = 0; r < 4; r++) {
        int t = m0 + wm * 64 + mi * 16 + lr * 4 + r;
        int n = n0 + wn * 64 + ni * 16 + lc;
        float v = acc[mi][ni][r];
        if (MODE == 0) {
          int c = n >> 11, e = n & 2047, h = e >> 7, d = e & 127;
          outb[(((size_t)c * NH + h) * T_SEQ + t) * HD + d] = f2bf(v);
        } else {
          outf[(size_t)t * N + n] = v;
        }
      }
}

// ---------------- RMSNorm + RoPE (in-place on q,k; layout [c][h][t][d]) ----------------
__global__ __launch_bounds__(256) void norm_rope(unsigned short* __restrict__ qkvb,
                                                 const float* __restrict__ cosT,
                                                 const float* __restrict__ sinT) {
  int r = blockIdx.x * 4 + (threadIdx.x >> 6);   // row over [c][h][t], c in {0,1}
  int lane = threadIdx.x & 63;
  int t = r % T_SEQ;
  unsigned short* row = qkvb + (size_t)r * HD;
  float f1 = bf2f(row[lane]), f2 = bf2f(row[lane + 64]);
  float ss = f1 * f1 + f2 * f2;
#pragma unroll
  for (int off = 32; off; off >>= 1) ss += __shfl_xor(ss, off, 64);
  float rs = rsqrtf(ss * (1.0f / 128.0f) + 1e-6f);
  f1 *= rs; f2 *= rs;
  float c_ = cosT[t * 64 + lane], s_ = sinT[t * 64 + lane];
  row[lane]      = f2bf(f1 * c_ + f2 * s_);
  row[lane + 64] = f2bf(-f1 * s_ + f2 * c_);
}

// ---------------- v' = l0*v + l1*ve, transposed to v_t[h][d][t] ----------------
__global__ __launch_bounds__(256) void vmix_transpose(const unsigned short* __restrict__ vb,
                                                      const float* __restrict__ ve,
                                                      const float* __restrict__ lam,
                                                      unsigned short* __restrict__ vt) {
  __shared__ float tile[64][65];
  const int h = blockIdx.z, t0 = blockIdx.x * 64, d0 = blockIdx.y * 64;
  const float l0 = lam[0], l1 = lam[1];
  const int tid = threadIdx.x;
  const int tl = tid >> 4, dl4 = (tid & 15) * 4;
#pragma unroll
  for (int i = 0; i < 4; i++) {
    int t_local = tl + i * 16;
    int t = t0 + t_local;
    const unsigned short* vp = vb + ((size_t)h * T_SEQ + t) * HD + d0 + dl4;
    const float* vep = ve + (size_t)t * HDIM + h * HD + d0 + dl4;
    u16x4 vv = *(const u16x4*)vp;
    float4 vef = *(const float4*)vep;
    tile[t_local][dl4 + 0] = l0 * bf2f(vv.x) + l1 * vef.x;
    tile[t_local][dl4 + 1] = l0 * bf2f(vv.y) + l1 * vef.y;
    tile[t_local][dl4 + 2] = l0 * bf2f(vv.z) + l1 * vef.z;
    tile[t_local][dl4 + 3] = l0 * bf2f(vv.w) + l1 * vef.w;
  }
  __syncthreads();
#pragma unroll
  for (int i = 0; i < 2; i++) {
    int idx = tid + i * 256;
    int d_local = idx >> 3, tloc = (idx & 7) * 8;
    u16x8 o;
#pragma unroll
    for (int j = 0; j < 8; j++) o[j] = f2bf(tile[tloc + j][d_local]);
    *(u16x8*)(vt + ((size_t)h * HD + d0 + d_local) * T_SEQ + t0 + tloc) = o;
  }
}

// ---------------- flash attention (causal), 4 waves, QBLK=64, KVBLK=64 ----------------
// qb,kb: [h][t][d] bf16; vt: [h][d][t] bf16; ao: [t][h*HD+d] bf16
__global__ __launch_bounds__(256) void attn_fwd(const unsigned short* __restrict__ qb,
                                                const unsigned short* __restrict__ kb,
                                                const unsigned short* __restrict__ vt,
                                                unsigned short* __restrict__ ao) {
  __shared__ unsigned short K_l[64 * 128];   // [kv][d], rows 256B, XOR-swizzled 16B slots
  __shared__ unsigned short V_l[128 * 64];   // [d][t], rows 128B, XOR-swizzled
  __shared__ unsigned short P_l[4][16 * 64]; // per-wave P, rows 128B, XOR-swizzled
  const int h = blockIdx.y;
  const int qt = gridDim.x - 1 - blockIdx.x;       // heavy tiles first
  const int tid = threadIdx.x, w = tid >> 6, lane = tid & 63;
  const int lr = lane >> 4, lc = lane & 15;
  const unsigned short* qh = qb + (size_t)h * T_SEQ * HD;
  const unsigned short* kh = kb + (size_t)h * T_SEQ * HD;
  const unsigned short* vh = vt + (size_t)h * HD * T_SEQ;

  // Q fragments in registers
  short8 qf[4];
  const int qrow = qt * 64 + w * 16 + lc;
#pragma unroll
  for (int kk = 0; kk < 4; kk++)
    qf[kk] = *(const short8*)(qh + (size_t)qrow * HD + kk * 32 + lr * 8);

  f32x4 accO[8] = {};
  float m_r[4], l_r[4];
#pragma unroll
  for (int r = 0; r < 4; r++) { m_r[r] = -1e30f; l_r[r] = 0.0f; }

  const int kcrow = (lane >> 4);       // K staging: 4 rows / 1KB chunk
  const int kcol16 = lane & 15;
  const int vcrow = (lane >> 3);       // V staging: 8 rows / 1KB chunk
  const int vslot0 = lane & 7;

  for (int kt = 0; kt <= qt; kt++) {
    __syncthreads();
#pragma unroll
    for (int i = 0; i < 4; i++) {
      // K tile [64][128]: chunk covers 4 rows of 256B
      int krow = (w * 4 + i) * 4 + kcrow;
      int kcol = (kcol16 ^ (krow & 7)) * 8;          // pre-swizzled source
      gload_lds16(kh + (size_t)(kt * 64 + krow) * HD + kcol, (char*)K_l + (w * 4 + i) * 1024);
      // V^T tile [128][64]: chunk covers 8 rows of 128B
      int vrow = (w * 4 + i) * 8 + vcrow;
      int vcol = (vslot0 ^ (vrow & 7)) * 8;
      gload_lds16(vh + (size_t)vrow * T_SEQ + kt * 64 + vcol, (char*)V_l + (w * 4 + i) * 1024);
    }
    __syncthreads();

    // S = Q K^T
    f32x4 accS[4] = {};
#pragma unroll
    for (int n = 0; n < 4; n++) {
#pragma unroll
      for (int kk = 0; kk < 4; kk++) {
        int krow = n * 16 + lc;
        int slot = (kk * 4 + lr) ^ (krow & 7);
        short8 kf = *(const short8*)((const char*)K_l + krow * 256 + slot * 16);
        accS[n] = __builtin_amdgcn_mfma_f32_16x16x32_bf16(qf[kk], kf, accS[n], 0, 0, 0);
      }
    }

    const float scale = 0.088388347648318447f;   // 1/sqrt(128)
    float sv[4][4];
#pragma unroll
    for (int n = 0; n < 4; n++)
#pragma unroll
      for (int r = 0; r < 4; r++) {
        float s = accS[n][r] * scale;
        if (kt == qt) {
          int kvl = n * 16 + lc, ql = w * 16 + lr * 4 + r;
          if (kvl > ql) s = -1e30f;
        }
        sv[n][r] = s;
      }

    float alpha[4];
#pragma unroll
    for (int r = 0; r < 4; r++) {
      float x = fmaxf(fmaxf(sv[0][r], sv[1][r]), fmaxf(sv[2][r], sv[3][r]));
#pragma unroll
      for (int off = 1; off < 16; off <<= 1) x = fmaxf(x, __shfl_xor(x, off, 16));
      float mn = fmaxf(m_r[r], x);
      alpha[r] = exp2f((m_r[r] - mn) * 1.44269504f);
      m_r[r] = mn;
    }

    float pv[4][4];
#pragma unroll
    for (int r = 0; r < 4; r++) {
      float s = 0.0f;
#pragma unroll
      for (int n = 0; n < 4; n++) {
        float p = exp2f((sv[n][r] - m_r[r]) * 1.44269504f);
        pv[n][r] = p; s += p;
      }
#pragma unroll
      for (int off = 1; off < 16; off <<= 1) s += __shfl_xor(s, off, 16);
      l_r[r] = l_r[r] * alpha[r] + s;
    }
#pragma unroll
    for (int dn = 0; dn < 8; dn++)
#pragma unroll
      for (int r = 0; r < 4; r++) accO[dn][r] *= alpha[r];

    // P -> per-wave LDS (swizzled), then PV
    unsigned short* Pw = P_l[w];
#pragma unroll
    for (int n = 0; n < 4; n++)
#pragma unroll
      for (int r = 0; r < 4; r++) {
        int row = lr * 4 + r, col = n * 16 + lc;
        int b = (row * 128 + col * 2) ^ ((row & 7) << 4);
        *(unsigned short*)((char*)Pw + b) = f2bf(pv[n][r]);
      }
    asm volatile("s_waitcnt lgkmcnt(0)" ::: "memory");

#pragma unroll
    for (int ks = 0; ks < 2; ks++) {
      int pslot = (ks * 4 + lr) ^ (lc & 7);
      short8 pf = *(const short8*)((const char*)Pw + lc * 128 + pslot * 16);
#pragma unroll
      for (int dn = 0; dn < 8; dn++) {
        int vrow = dn * 16 + lc;
        int vslot = (ks * 4 + lr) ^ (vrow & 7);
        short8 vf = *(const short8*)((const char*)V_l + vrow * 128 + vslot * 16);
        accO[dn] = __builtin_amdgcn_mfma_f32_16x16x32_bf16(pf, vf, accO[dn], 0, 0, 0);
      }
    }
  }

  // epilogue: divide by l, write [t][h*HD+d]
#pragma unroll
  for (int dn = 0; dn < 8; dn++)
#pragma unroll
    for (int r = 0; r < 4; r++) {
      int t = qt * 64 + w * 16 + lr * 4 + r;
      float v = accO[dn][r] / l_r[r];
      ao[(size_t)t * HDIM + h * HD + dn * 16 + lc] = f2bf(v);
    }
}

// ---------------- launch ----------------
extern "C" void kernel_launch(void* const* d_in, const int* in_sizes, int n_in,
                              void* d_out, int out_size, void* d_ws, size_t ws_size,
                              hipStream_t stream) {
  const float* x      = (const float*)d_in[0];
  const float* ve     = (const float*)d_in[1];
  const float* lam    = (const float*)d_in[2];
  const float* qkv_w  = (const float*)d_in[3];
  const float* proj_w = (const float*)d_in[4];
  float* out = (float*)d_out;

  char* p = (char*)d_ws;
  float* cosT = (float*)p;            p += (size_t)T_SEQ * 64 * 4;
  float* sinT = (float*)p;            p += (size_t)T_SEQ * 64 * 4;
  unsigned short* xb   = (unsigned short*)p; p += (size_t)T_SEQ * DIM * 2;
  unsigned short* wqb  = (unsigned short*)p; p += (size_t)3 * HDIM * DIM * 2;
  unsigned short* pwb  = (unsigned short*)p; p += (size_t)DIM * HDIM * 2;
  unsigned short* qkvb = (unsigned short*)p; p += (size_t)3 * NH * T_SEQ * HD * 2;
  unsigned short* vtb  = (unsigned short*)p; p += (size_t)NH * HD * T_SEQ * 2;
  unsigned short* aob  = (unsigned short*)p; p += (size_t)T_SEQ * HDIM * 2;

  cvt_f32_bf16<<<(T_SEQ * DIM / 4 + 255) / 256, 256, 0, stream>>>(x, xb, T_SEQ * DIM / 4);
  cvt_f32_bf16<<<(3 * HDIM * DIM / 4 + 255) / 256, 256, 0, stream>>>(qkv_w, wqb, 3 * HDIM * DIM / 4);
  cvt_f32_bf16<<<(DIM * HDIM / 4 + 255) / 256, 256, 0, stream>>>(proj_w, pwb, DIM * HDIM / 4);
  rope_tables<<<(T_SEQ * 64 + 255) / 256, 256, 0, stream>>>(cosT, sinT);

  gemm_bt<0><<<dim3(T_SEQ / 128, 3 * HDIM / 128), 256, 0, stream>>>(xb, wqb, DIM, qkvb, nullptr, 3 * HDIM);
  norm_rope<<<2 * NH * T_SEQ / 4, 256, 0, stream>>>(qkvb, cosT, sinT);
  vmix_transpose<<<dim3(T_SEQ / 64, HD / 64, NH), 256, 0, stream>>>(
      qkvb + (size_t)2 * NH * T_SEQ * HD, ve, lam, vtb);
  attn_fwd<<<dim3(T_SEQ / 64, NH), 256, 0, stream>>>(qkvb, qkvb + (size_t)NH * T_SEQ * HD, vtb, aob);
  gemm_bt<1><<<dim3(T_SEQ / 128, HDIM / 128), 256, 0, stream>>>(aob, pwb, HDIM, nullptr, out, HDIM);
}

// Round 2
// 440.617 us; speedup vs baseline: 1.9641x; 1.9641x over previous
//
#include <hip/hip_runtime.h>
#include <cstdint>
#include <cstddef>

// ---------------- constants ----------------
constexpr int T_SEQ = 4096;
constexpr int NH    = 16;
constexpr int HD    = 128;
constexpr int DIM   = 2048;
constexpr int HDIM  = 2048;   // NH*HD

typedef __attribute__((ext_vector_type(8))) short  short8;
typedef __attribute__((ext_vector_type(4))) float  f32x4;
typedef __attribute__((ext_vector_type(8))) unsigned short u16x8;
typedef __attribute__((ext_vector_type(4))) unsigned short u16x4;

__device__ __forceinline__ unsigned short f2bf(float f) {
  unsigned u = __float_as_uint(f);
  return (unsigned short)((u + 0x7FFFu + ((u >> 16) & 1u)) >> 16);  // RNE
}
__device__ __forceinline__ float bf2f(unsigned short h) {
  return __uint_as_float(((unsigned)h) << 16);
}
__device__ __forceinline__ void gload_lds16(const void* g, void* l) {
  __builtin_amdgcn_global_load_lds((const __attribute__((address_space(1))) void*)g,
                                   (__attribute__((address_space(3))) void*)l, 16, 0, 0);
}

// ---------------- fp32 -> bf16 convert ----------------
__global__ __launch_bounds__(256) void cvt_f32_bf16(const float* __restrict__ in,
                                                    unsigned short* __restrict__ out, int n4) {
  int i = blockIdx.x * 256 + threadIdx.x;
  if (i < n4) {
    float4 v = ((const float4*)in)[i];
    u16x4 o; o.x = f2bf(v.x); o.y = f2bf(v.y); o.z = f2bf(v.z); o.w = f2bf(v.w);
    ((u16x4*)out)[i] = o;
  }
}

// ---------------- RoPE tables ----------------
__global__ __launch_bounds__(256) void rope_tables(float* __restrict__ cosT, float* __restrict__ sinT) {
  int idx = blockIdx.x * 256 + threadIdx.x;           // T_SEQ*64
  if (idx >= T_SEQ * 64) return;
  int t = idx >> 6, i = idx & 63;
  float ang = (i < 32) ? exp2f(-10.0f * (float)i / 31.0f) : 0.0f;  // (1/1024)^(i/31)
  float th = (float)t * ang;
  cosT[idx] = cosf(th);
  sinT[idx] = sinf(th);
}

// ---------------- GEMM: C = A * B^T  (A:[M][K] bf16, B:[N][K] bf16) ----------------
// 128x128 tile, BK=64, 4 waves (2x2), 16x16x32 MFMA. MODE 0: write bf16 into qkv layout
// [c][h][t][d]; MODE 1: write fp32 [t][n].
template <int MODE>
__global__ __launch_bounds__(256) void gemm_bt(const unsigned short* __restrict__ A,
                                               const unsigned short* __restrict__ B,
                                               int K, unsigned short* __restrict__ outb,
                                               float* __restrict__ outf, int N) {
  __shared__ unsigned short As[128 * 64];
  __shared__ unsigned short Bs[128 * 64];
  const int tid = threadIdx.x;
  const int w = tid >> 6, lane = tid & 63;
  const int wm = w >> 1, wn = w & 1;
  const int m0 = blockIdx.x * 128, n0 = blockIdx.y * 128;
  const int lr = lane >> 4, lc = lane & 15;
  const int srow = lane >> 3, scol = (lane & 7) * 8;   // staging: 8 rows x 64 cols per 1KB chunk

  f32x4 acc[4][4] = {};
  const int nkt = K >> 6;
  for (int kt = 0; kt < nkt; kt++) {
    __syncthreads();
    const int k0 = kt * 64;
#pragma unroll
    for (int i = 0; i < 4; i++) {
      int row = (w * 4 + i) * 8 + srow;
      gload_lds16(A + (size_t)(m0 + row) * K + k0 + scol, (char*)As + (w * 4 + i) * 1024);
      gload_lds16(B + (size_t)(n0 + row) * K + k0 + scol, (char*)Bs + (w * 4 + i) * 1024);
    }
    __syncthreads();
#pragma unroll
    for (int kk = 0; kk < 2; kk++) {
      short8 a[4], b[4];
#pragma unroll
      for (int mi = 0; mi < 4; mi++)
        a[mi] = *(const short8*)(As + (wm * 64 + mi * 16 + lc) * 64 + kk * 32 + lr * 8);
#pragma unroll
      for (int ni = 0; ni < 4; ni++)
        b[ni] = *(const short8*)(Bs + (wn * 64 + ni * 16 + lc) * 64 + kk * 32 + lr * 8);
#pragma unroll
      for (int mi = 0; mi < 4; mi++)
#pragma unroll
        for (int ni = 0; ni < 4; ni++)
          acc[mi][ni] = __builtin_amdgcn_mfma_f32_16x16x32_bf16(a[mi], b[ni], acc[mi][ni], 0, 0, 0);
    }
  }
#pragma unroll
  for (int mi = 0; mi < 4; mi++)
#pragma unroll
    for (int ni = 0; ni < 4; ni++)
#pragma unroll
      for (int r = 0; r < 4; r++) {
        int t = m0 + wm * 64 + mi * 16 + lr * 4 + r;
        int n = n0 + wn * 64 + ni * 16 + lc;
        float v = acc[mi][ni][r];
        if (MODE == 0) {
          int c = n >> 11, e = n & 2047, h = e >> 7, d = e & 127;
          outb[(((size_t)c * NH + h) * T_SEQ + t) * HD + d] = f2bf(v);
        } else {
          outf[(size_t)t * N + n] = v;
        }
      }
}

// ---------------- RMSNorm + RoPE (in-place on q,k; layout [c][h][t][d]) ----------------
__global__ __launch_bounds__(256) void norm_rope(unsigned short* __restrict__ qkvb,
                                                 const float* __restrict__ cosT,
                                                 const float* __restrict__ sinT) {
  int r = blockIdx.x * 4 + (threadIdx.x >> 6);   // row over [c][h][t], c in {0,1}
  int lane = threadIdx.x & 63;
  int t = r % T_SEQ;
  unsigned short* row = qkvb + (size_t)r * HD;
  float f1 = bf2f(row[lane]), f2 = bf2f(row[lane + 64]);
  float ss = f1 * f1 + f2 * f2;
#pragma unroll
  for (int off = 32; off; off >>= 1) ss += __shfl_xor(ss, off, 64);
  float rs = rsqrtf(ss * (1.0f / 128.0f) + 1e-6f);
  f1 *= rs; f2 *= rs;
  float c_ = cosT[t * 64 + lane], s_ = sinT[t * 64 + lane];
  row[lane]      = f2bf(f1 * c_ + f2 * s_);
  row[lane + 64] = f2bf(-f1 * s_ + f2 * c_);
}

// ---------------- v' = l0*v + l1*ve, transposed to v_t[h][d][t] ----------------
__global__ __launch_bounds__(256) void vmix_transpose(const unsigned short* __restrict__ vb,
                                                      const float* __restrict__ ve,
                                                      const float* __restrict__ lam,
                                                      unsigned short* __restrict__ vt) {
  __shared__ float tile[64][65];
  const int h = blockIdx.z, t0 = blockIdx.x * 64, d0 = blockIdx.y * 64;
  const float l0 = lam[0], l1 = lam[1];
  const int tid = threadIdx.x;
  const int tl = tid >> 4, dl4 = (tid & 15) * 4;
#pragma unroll
  for (int i = 0; i < 4; i++) {
    int t_local = tl + i * 16;
    int t = t0 + t_local;
    const unsigned short* vp = vb + ((size_t)h * T_SEQ + t) * HD + d0 + dl4;
    const float* vep = ve + (size_t)t * HDIM + h * HD + d0 + dl4;
    u16x4 vv = *(const u16x4*)vp;
    float4 vef = *(const float4*)vep;
    tile[t_local][dl4 + 0] = l0 * bf2f(vv.x) + l1 * vef.x;
    tile[t_local][dl4 + 1] = l0 * bf2f(vv.y) + l1 * vef.y;
    tile[t_local][dl4 + 2] = l0 * bf2f(vv.z) + l1 * vef.z;
    tile[t_local][dl4 + 3] = l0 * bf2f(vv.w) + l1 * vef.w;
  }
  __syncthreads();
#pragma unroll
  for (int i = 0; i < 2; i++) {
    int idx = tid + i * 256;
    int d_local = idx >> 3, tloc = (idx & 7) * 8;
    u16x8 o;
#pragma unroll
    for (int j = 0; j < 8; j++) o[j] = f2bf(tile[tloc + j][d_local]);
    *(u16x8*)(vt + ((size_t)h * HD + d0 + d_local) * T_SEQ + t0 + tloc) = o;
  }
}

// ---------------- flash attention (causal), 4 waves, QBLK=64, KVBLK=64 ----------------
// Paired q-tiles for load balance (block pr handles qt=63-pr then qt=pr: 65 kv-iters each).
// Double-buffered K/V staging: per iter {vmcnt(0); barrier; STAGE(next); compute(cur)} —
// prefetch latency hides under compute; one barrier per iter.
// qb,kb: [h][t][d] bf16; vt: [h][d][t] bf16; ao: [t][h*HD+d] bf16
__global__ __launch_bounds__(256) void attn_fwd(const unsigned short* __restrict__ qb,
                                                const unsigned short* __restrict__ kb,
                                                const unsigned short* __restrict__ vt,
                                                unsigned short* __restrict__ ao) {
  __shared__ unsigned short K_l[2][64 * 128];   // [kv][d], rows 256B, XOR-swizzled 16B slots
  __shared__ unsigned short V_l[2][128 * 64];   // [d][t], rows 128B, XOR-swizzled
  __shared__ unsigned short P_l[4][16 * 64];    // per-wave P, rows 128B, XOR-swizzled
  const int h = blockIdx.y;
  const int pr = blockIdx.x;                    // 0..31 (pair index)
  const int tid = threadIdx.x, w = tid >> 6, lane = tid & 63;
  const int lr = lane >> 4, lc = lane & 15;
  const unsigned short* qh = qb + (size_t)h * T_SEQ * HD;
  const unsigned short* kh = kb + (size_t)h * T_SEQ * HD;
  const unsigned short* vh = vt + (size_t)h * HD * T_SEQ;

  const int kcrow = (lane >> 4);       // K staging: 4 rows / 1KB chunk
  const int kcol16 = lane & 15;
  const int vcrow = (lane >> 3);       // V staging: 8 rows / 1KB chunk
  const int vslot0 = lane & 7;

  auto STAGE = [&](int buf, int kt) {
#pragma unroll
    for (int i = 0; i < 4; i++) {
      int krow = (w * 4 + i) * 4 + kcrow;
      int kcol = (kcol16 ^ (krow & 7)) * 8;          // pre-swizzled source
      gload_lds16(kh + (size_t)(kt * 64 + krow) * HD + kcol, (char*)K_l[buf] + (w * 4 + i) * 1024);
      int vrow = (w * 4 + i) * 8 + vcrow;
      int vcol = (vslot0 ^ (vrow & 7)) * 8;
      gload_lds16(vh + (size_t)vrow * T_SEQ + kt * 64 + vcol, (char*)V_l[buf] + (w * 4 + i) * 1024);
    }
  };

  const float SCL2E = 0.088388347648318447f * 1.44269504f;  // 1/sqrt(128) * log2(e)

#pragma unroll 1
  for (int which = 0; which < 2; ++which) {
    const int qt = which ? pr : (63 - pr);     // heavy tile first
    // Q fragments in registers
    short8 qf[4];
    const int qrow = qt * 64 + w * 16 + lc;
#pragma unroll
    for (int kk = 0; kk < 4; kk++)
      qf[kk] = *(const short8*)(qh + (size_t)qrow * HD + kk * 32 + lr * 8);

    f32x4 accO[8] = {};
    float m_r[4], l_r[4];
#pragma unroll
    for (int r = 0; r < 4; r++) { m_r[r] = -1e30f; l_r[r] = 0.0f; }

    const int nkt = qt + 1;
    __syncthreads();                 // all waves done reading LDS of previous tile
    STAGE(0, 0);

#pragma unroll 1
    for (int kt = 0; kt < nkt; kt++) {
      const int cur = kt & 1;
      asm volatile("s_waitcnt vmcnt(0)" ::: "memory");  // own stage(cur) loads landed
      __syncthreads();                                  // all waves' stage(cur) landed
      if (kt + 1 < nkt) STAGE(cur ^ 1, kt + 1);         // prefetch next under compute

      // S = Q K^T  (in exp2 domain: pre-scaled by 1/sqrt(d)*log2e)
      f32x4 accS[4] = {};
#pragma unroll
      for (int n = 0; n < 4; n++) {
#pragma unroll
        for (int kk = 0; kk < 4; kk++) {
          int krow = n * 16 + lc;
          int slot = (kk * 4 + lr) ^ (krow & 7);
          short8 kf = *(const short8*)((const char*)K_l[cur] + krow * 256 + slot * 16);
          accS[n] = __builtin_amdgcn_mfma_f32_16x16x32_bf16(qf[kk], kf, accS[n], 0, 0, 0);
        }
      }

      float sv[4][4];
#pragma unroll
      for (int n = 0; n < 4; n++)
#pragma unroll
        for (int r = 0; r < 4; r++) {
          float s = accS[n][r] * SCL2E;
          if (kt == qt) {
            int kvl = n * 16 + lc, ql = w * 16 + lr * 4 + r;
            if (kvl > ql) s = -1e30f;
          }
          sv[n][r] = s;
        }

      float alpha[4];
#pragma unroll
      for (int r = 0; r < 4; r++) {
        float x = fmaxf(fmaxf(sv[0][r], sv[1][r]), fmaxf(sv[2][r], sv[3][r]));
#pragma unroll
        for (int off = 1; off < 16; off <<= 1) x = fmaxf(x, __shfl_xor(x, off, 16));
        float mn = fmaxf(m_r[r], x);
        alpha[r] = exp2f(m_r[r] - mn);
        m_r[r] = mn;
      }

      float pv[4][4];
#pragma unroll
      for (int r = 0; r < 4; r++) {
        float s = 0.0f;
#pragma unroll
        for (int n = 0; n < 4; n++) {
          float p = exp2f(sv[n][r] - m_r[r]);
          pv[n][r] = p; s += p;
        }
#pragma unroll
        for (int off = 1; off < 16; off <<= 1) s += __shfl_xor(s, off, 16);
        l_r[r] = l_r[r] * alpha[r] + s;
      }
#pragma unroll
      for (int dn = 0; dn < 8; dn++)
#pragma unroll
        for (int r = 0; r < 4; r++) accO[dn][r] *= alpha[r];

      // P -> per-wave LDS (swizzled), then PV
      unsigned short* Pw = P_l[w];
#pragma unroll
      for (int n = 0; n < 4; n++)
#pragma unroll
        for (int r = 0; r < 4; r++) {
          int row = lr * 4 + r, col = n * 16 + lc;
          int b = (row * 128 + col * 2) ^ ((row & 7) << 4);
          *(unsigned short*)((char*)Pw + b) = f2bf(pv[n][r]);
        }
      asm volatile("s_waitcnt lgkmcnt(0)" ::: "memory");

#pragma unroll
      for (int ks = 0; ks < 2; ks++) {
        int pslot = (ks * 4 + lr) ^ (lc & 7);
        short8 pf = *(const short8*)((const char*)Pw + lc * 128 + pslot * 16);
#pragma unroll
        for (int dn = 0; dn < 8; dn++) {
          int vrow = dn * 16 + lc;
          int vslot = (ks * 4 + lr) ^ (vrow & 7);
          short8 vf = *(const short8*)((const char*)V_l[cur] + vrow * 128 + vslot * 16);
          accO[dn] = __builtin_amdgcn_mfma_f32_16x16x32_bf16(pf, vf, accO[dn], 0, 0, 0);
        }
      }
    }

    // epilogue: divide by l, write [t][h*HD+d]
#pragma unroll
    for (int dn = 0; dn < 8; dn++)
#pragma unroll
      for (int r = 0; r < 4; r++) {
        int t = qt * 64 + w * 16 + lr * 4 + r;
        float v = accO[dn][r] / l_r[r];
        ao[(size_t)t * HDIM + h * HD + dn * 16 + lc] = f2bf(v);
      }
  }
}

// ---------------- launch ----------------
extern "C" void kernel_launch(void* const* d_in, const int* in_sizes, int n_in,
                              void* d_out, int out_size, void* d_ws, size_t ws_size,
                              hipStream_t stream) {
  const float* x      = (const float*)d_in[0];
  const float* ve     = (const float*)d_in[1];
  const float* lam    = (const float*)d_in[2];
  const float* qkv_w  = (const float*)d_in[3];
  const float* proj_w = (const float*)d_in[4];
  float* out = (float*)d_out;

  char* p = (char*)d_ws;
  float* cosT = (float*)p;            p += (size_t)T_SEQ * 64 * 4;
  float* sinT = (float*)p;            p += (size_t)T_SEQ * 64 * 4;
  unsigned short* xb   = (unsigned short*)p; p += (size_t)T_SEQ * DIM * 2;
  unsigned short* wqb  = (unsigned short*)p; p += (size_t)3 * HDIM * DIM * 2;
  unsigned short* pwb  = (unsigned short*)p; p += (size_t)DIM * HDIM * 2;
  unsigned short* qkvb = (unsigned short*)p; p += (size_t)3 * NH * T_SEQ * HD * 2;
  unsigned short* vtb  = (unsigned short*)p; p += (size_t)NH * HD * T_SEQ * 2;
  unsigned short* aob  = (unsigned short*)p; p += (size_t)T_SEQ * HDIM * 2;

  cvt_f32_bf16<<<(T_SEQ * DIM / 4 + 255) / 256, 256, 0, stream>>>(x, xb, T_SEQ * DIM / 4);
  cvt_f32_bf16<<<(3 * HDIM * DIM / 4 + 255) / 256, 256, 0, stream>>>(qkv_w, wqb, 3 * HDIM * DIM / 4);
  cvt_f32_bf16<<<(DIM * HDIM / 4 + 255) / 256, 256, 0, stream>>>(proj_w, pwb, DIM * HDIM / 4);
  rope_tables<<<(T_SEQ * 64 + 255) / 256, 256, 0, stream>>>(cosT, sinT);

  gemm_bt<0><<<dim3(T_SEQ / 128, 3 * HDIM / 128), 256, 0, stream>>>(xb, wqb, DIM, qkvb, nullptr, 3 * HDIM);
  norm_rope<<<2 * NH * T_SEQ / 4, 256, 0, stream>>>(qkvb, cosT, sinT);
  vmix_transpose<<<dim3(T_SEQ / 64, HD / 64, NH), 256, 0, stream>>>(
      qkvb + (size_t)2 * NH * T_SEQ * HD, ve, lam, vtb);
  attn_fwd<<<dim3(32, NH), 256, 0, stream>>>(qkvb, qkvb + (size_t)NH * T_SEQ * HD, vtb, aob);
  gemm_bt<1><<<dim3(T_SEQ / 128, HDIM / 128), 256, 0, stream>>>(aob, pwb, HDIM, nullptr, out, HDIM);
}

// Round 3
// 415.120 us; speedup vs baseline: 2.0847x; 1.0614x over previous
//
#include <hip/hip_runtime.h>
#include <cstdint>
#include <cstddef>

// ---------------- constants ----------------
constexpr int T_SEQ = 4096;
constexpr int NH    = 16;
constexpr int HD    = 128;
constexpr int DIM   = 2048;
constexpr int HDIM  = 2048;   // NH*HD

typedef __attribute__((ext_vector_type(8)))  short  short8;
typedef __attribute__((ext_vector_type(4)))  float  f32x4;
typedef __attribute__((ext_vector_type(16))) float  f32x16;
typedef __attribute__((ext_vector_type(8)))  unsigned short u16x8;
typedef __attribute__((ext_vector_type(4)))  unsigned short u16x4;
typedef __attribute__((ext_vector_type(4)))  unsigned uint4v;

__device__ __forceinline__ unsigned short f2bf(float f) {
  unsigned u = __float_as_uint(f);
  return (unsigned short)((u + 0x7FFFu + ((u >> 16) & 1u)) >> 16);  // RNE
}
__device__ __forceinline__ float bf2f(unsigned short h) {
  return __uint_as_float(((unsigned)h) << 16);
}
__device__ __forceinline__ void gload_lds16(const void* g, void* l) {
  __builtin_amdgcn_global_load_lds((const __attribute__((address_space(1))) void*)g,
                                   (__attribute__((address_space(3))) void*)l, 16, 0, 0);
}

// ---------------- fp32 -> bf16 convert ----------------
__global__ __launch_bounds__(256) void cvt_f32_bf16(const float* __restrict__ in,
                                                    unsigned short* __restrict__ out, int n4) {
  int i = blockIdx.x * 256 + threadIdx.x;
  if (i < n4) {
    float4 v = ((const float4*)in)[i];
    u16x4 o; o.x = f2bf(v.x); o.y = f2bf(v.y); o.z = f2bf(v.z); o.w = f2bf(v.w);
    ((u16x4*)out)[i] = o;
  }
}

// ---------------- RoPE tables ----------------
__global__ __launch_bounds__(256) void rope_tables(float* __restrict__ cosT, float* __restrict__ sinT) {
  int idx = blockIdx.x * 256 + threadIdx.x;           // T_SEQ*64
  if (idx >= T_SEQ * 64) return;
  int t = idx >> 6, i = idx & 63;
  float ang = (i < 32) ? exp2f(-10.0f * (float)i / 31.0f) : 0.0f;  // (1/1024)^(i/31)
  float th = (float)t * ang;
  cosT[idx] = cosf(th);
  sinT[idx] = sinf(th);
}

// ---------------- GEMM: C = A * B^T  (A:[M][K] bf16, B:[N][K] bf16) ----------------
template <int MODE>
__global__ __launch_bounds__(256) void gemm_bt(const unsigned short* __restrict__ A,
                                               const unsigned short* __restrict__ B,
                                               int K, unsigned short* __restrict__ outb,
                                               float* __restrict__ outf, int N) {
  __shared__ unsigned short As[128 * 64];
  __shared__ unsigned short Bs[128 * 64];
  const int tid = threadIdx.x;
  const int w = tid >> 6, lane = tid & 63;
  const int wm = w >> 1, wn = w & 1;
  const int m0 = blockIdx.x * 128, n0 = blockIdx.y * 128;
  const int lr = lane >> 4, lc = lane & 15;
  const int srow = lane >> 3, scol = (lane & 7) * 8;   // staging: 8 rows x 64 cols per 1KB chunk

  f32x4 acc[4][4] = {};
  const int nkt = K >> 6;
  for (int kt = 0; kt < nkt; kt++) {
    __syncthreads();
    const int k0 = kt * 64;
#pragma unroll
    for (int i = 0; i < 4; i++) {
      int row = (w * 4 + i) * 8 + srow;
      gload_lds16(A + (size_t)(m0 + row) * K + k0 + scol, (char*)As + (w * 4 + i) * 1024);
      gload_lds16(B + (size_t)(n0 + row) * K + k0 + scol, (char*)Bs + (w * 4 + i) * 1024);
    }
    __syncthreads();
#pragma unroll
    for (int kk = 0; kk < 2; kk++) {
      short8 a[4], b[4];
#pragma unroll
      for (int mi = 0; mi < 4; mi++)
        a[mi] = *(const short8*)(As + (wm * 64 + mi * 16 + lc) * 64 + kk * 32 + lr * 8);
#pragma unroll
      for (int ni = 0; ni < 4; ni++)
        b[ni] = *(const short8*)(Bs + (wn * 64 + ni * 16 + lc) * 64 + kk * 32 + lr * 8);
#pragma unroll
      for (int mi = 0; mi < 4; mi++)
#pragma unroll
        for (int ni = 0; ni < 4; ni++)
          acc[mi][ni] = __builtin_amdgcn_mfma_f32_16x16x32_bf16(a[mi], b[ni], acc[mi][ni], 0, 0, 0);
    }
  }
#pragma unroll
  for (int mi = 0; mi < 4; mi++)
#pragma unroll
    for (int ni = 0; ni < 4; ni++)
#pragma unroll
      for (int r = 0; r < 4; r++) {
        int t = m0 + wm * 64 + mi * 16 + lr * 4 + r;
        int n = n0 + wn * 64 + ni * 16 + lc;
        float v = acc[mi][ni][r];
        if (MODE == 0) {
          int c = n >> 11, e = n & 2047, h = e >> 7, d = e & 127;
          outb[(((size_t)c * NH + h) * T_SEQ + t) * HD + d] = f2bf(v);
        } else {
          outf[(size_t)t * N + n] = v;
        }
      }
}

// ---------------- RMSNorm + RoPE (in-place on q,k; layout [c][h][t][d]) ----------------
__global__ __launch_bounds__(256) void norm_rope(unsigned short* __restrict__ qkvb,
                                                 const float* __restrict__ cosT,
                                                 const float* __restrict__ sinT) {
  int r = blockIdx.x * 4 + (threadIdx.x >> 6);   // row over [c][h][t], c in {0,1}
  int lane = threadIdx.x & 63;
  int t = r % T_SEQ;
  unsigned short* row = qkvb + (size_t)r * HD;
  float f1 = bf2f(row[lane]), f2 = bf2f(row[lane + 64]);
  float ss = f1 * f1 + f2 * f2;
#pragma unroll
  for (int off = 32; off; off >>= 1) ss += __shfl_xor(ss, off, 64);
  float rs = rsqrtf(ss * (1.0f / 128.0f) + 1e-6f);
  f1 *= rs; f2 *= rs;
  float c_ = cosT[t * 64 + lane], s_ = sinT[t * 64 + lane];
  row[lane]      = f2bf(f1 * c_ + f2 * s_);
  row[lane + 64] = f2bf(-f1 * s_ + f2 * c_);
}

// ---------------- v' = l0*v + l1*ve, transposed to v_t[h][d][t] ----------------
__global__ __launch_bounds__(256) void vmix_transpose(const unsigned short* __restrict__ vb,
                                                      const float* __restrict__ ve,
                                                      const float* __restrict__ lam,
                                                      unsigned short* __restrict__ vt) {
  __shared__ float tile[64][65];
  const int h = blockIdx.z, t0 = blockIdx.x * 64, d0 = blockIdx.y * 64;
  const float l0 = lam[0], l1 = lam[1];
  const int tid = threadIdx.x;
  const int tl = tid >> 4, dl4 = (tid & 15) * 4;
#pragma unroll
  for (int i = 0; i < 4; i++) {
    int t_local = tl + i * 16;
    int t = t0 + t_local;
    const unsigned short* vp = vb + ((size_t)h * T_SEQ + t) * HD + d0 + dl4;
    const float* vep = ve + (size_t)t * HDIM + h * HD + d0 + dl4;
    u16x4 vv = *(const u16x4*)vp;
    float4 vef = *(const float4*)vep;
    tile[t_local][dl4 + 0] = l0 * bf2f(vv.x) + l1 * vef.x;
    tile[t_local][dl4 + 1] = l0 * bf2f(vv.y) + l1 * vef.y;
    tile[t_local][dl4 + 2] = l0 * bf2f(vv.z) + l1 * vef.z;
    tile[t_local][dl4 + 3] = l0 * bf2f(vv.w) + l1 * vef.w;
  }
  __syncthreads();
#pragma unroll
  for (int i = 0; i < 2; i++) {
    int idx = tid + i * 256;
    int d_local = idx >> 3, tloc = (idx & 7) * 8;
    u16x8 o;
#pragma unroll
    for (int j = 0; j < 8; j++) o[j] = f2bf(tile[tloc + j][d_local]);
    *(u16x8*)(vt + ((size_t)h * HD + d0 + d_local) * T_SEQ + t0 + tloc) = o;
  }
}

// ---------------- flash attention (causal), swapped-operand 32x32x16 ----------------
// 4 warps x 32 q-rows = QBLK 128, KVBLK 64. Swapped QK^T (mfma(K,Q)) puts a full P-row
// per lane-pair (lane owns q=lane&31, kv half selected by hi=lane>>5) -> in-register
// softmax (tree reduce + one shfl_xor(32)). Swapped PV (mfma(V^T,P^T)) keeps m/l/alpha
// per-lane scalars; P feeds MFMA B-operand via cvt_pk_bf16 + half-exchange (no P LDS).
// Pairing (31-pr, pr): every block exactly 66 kv-iters, 256 blocks = 1/CU.
__global__ __launch_bounds__(256, 1) void attn_fwd(const unsigned short* __restrict__ qb,
                                                   const unsigned short* __restrict__ kb,
                                                   const unsigned short* __restrict__ vt,
                                                   unsigned short* __restrict__ ao) {
  __shared__ unsigned short K_l[2][64 * 128];   // [kv][d], rows 256B, XOR-swizzled 16B slots
  __shared__ unsigned short V_l[2][128 * 64];   // [d][t], rows 128B, XOR-swizzled
  const int h = blockIdx.y;
  const int pr = blockIdx.x;                    // 0..15
  const int tid = threadIdx.x, w = tid >> 6, lane = tid & 63;
  const int l31 = lane & 31, hi = lane >> 5, r7 = l31 & 7;
  const unsigned short* qh = qb + (size_t)h * T_SEQ * HD;
  const unsigned short* kh = kb + (size_t)h * T_SEQ * HD;
  const unsigned short* vh = vt + (size_t)h * HD * T_SEQ;

  const int kcrow = lane >> 4, kcol16 = lane & 15;   // K staging: 4 rows / 1KB chunk
  const int vcrow = lane >> 3, vslot0 = lane & 7;    // V staging: 8 rows / 1KB chunk

  auto STAGE = [&](int buf, int kt) {
#pragma unroll
    for (int i = 0; i < 4; i++) {
      int krow = (w * 4 + i) * 4 + kcrow;
      int kcol = (kcol16 ^ (krow & 7)) * 8;          // pre-swizzled source (rule #21)
      gload_lds16(kh + (size_t)(kt * 64 + krow) * HD + kcol, (char*)K_l[buf] + (w * 4 + i) * 1024);
      int vrow = (w * 4 + i) * 8 + vcrow;
      int vcol = (vslot0 ^ (vrow & 7)) * 8;
      gload_lds16(vh + (size_t)vrow * T_SEQ + kt * 64 + vcol, (char*)V_l[buf] + (w * 4 + i) * 1024);
    }
  };

  const float SCL2E = 0.088388347648318447f * 1.44269504f;  // 1/sqrt(128) * log2(e)

#pragma unroll 1
  for (int which = 0; which < 2; ++which) {
    const int qt = which ? pr : (31 - pr);     // heavy tile first
    const int nkt = 2 * (qt + 1);
    const int q_row = qt * 128 + w * 32 + l31; // lane's q (shared with lane^32)

    short8 qf[8];                              // B-frag: Q[q_row][16dk + 8hi + 0..7]
#pragma unroll
    for (int dk = 0; dk < 8; dk++)
      qf[dk] = *(const short8*)(qh + (size_t)q_row * HD + dk * 16 + hi * 8);

    f32x16 accO[4] = {};                       // O^T: col=q, rows d (4 tiles of 32)
    float m_r = -1e30f, l_r = 0.0f;

    __syncthreads();                           // prev q-tile's LDS reads done
    STAGE(0, 0);

#pragma unroll 1
    for (int kt = 0; kt < nkt; kt++) {
      const int cur = kt & 1;
      asm volatile("s_waitcnt vmcnt(0)" ::: "memory");  // stage(cur) landed
      __syncthreads();
      if (kt + 1 < nkt) STAGE(cur ^ 1, kt + 1);         // prefetch under compute

      // ---- S^T = K Q^T : 2 kv-subtiles x 8 d-steps ----
      f32x16 accS0 = {}, accS1 = {};
      const char* Kb = (const char*)K_l[cur] + l31 * 256;
#pragma unroll
      for (int dk = 0; dk < 8; dk++) {
        int sl = ((2 * dk + hi) ^ r7) * 16;
        short8 k0 = *(const short8*)(Kb + sl);
        short8 k1 = *(const short8*)(Kb + 32 * 256 + sl);
        accS0 = __builtin_amdgcn_mfma_f32_32x32x16_bf16(k0, qf[dk], accS0, 0, 0, 0);
        accS1 = __builtin_amdgcn_mfma_f32_32x32x16_bf16(k1, qf[dk], accS1, 0, 0, 0);
      }

      // ---- scale + causal mask; lane holds P[q_row][kv], kv = 32ts+(r&3)+8(r>>2)+4hi ----
      float p[32];
      const bool need_mask = (kt * 64 + 63) > (qt * 128 + w * 32);
      if (need_mask) {
#pragma unroll
        for (int r = 0; r < 16; r++) {
          int kv0 = kt * 64 + (r & 3) + 8 * (r >> 2) + 4 * hi;
          p[r]      = (kv0      > q_row) ? -1e30f : accS0[r] * SCL2E;
          p[16 + r] = (kv0 + 32 > q_row) ? -1e30f : accS1[r] * SCL2E;
        }
      } else {
#pragma unroll
        for (int r = 0; r < 16; r++) { p[r] = accS0[r] * SCL2E; p[16 + r] = accS1[r] * SCL2E; }
      }

      // ---- row max: in-register tree + one cross-half shfl ----
      float t16[16];
#pragma unroll
      for (int i = 0; i < 16; i++) t16[i] = fmaxf(p[i], p[i + 16]);
#pragma unroll
      for (int st = 8; st >= 1; st >>= 1)
#pragma unroll
        for (int i = 0; i < st; i++) t16[i] = fmaxf(t16[i], t16[i + st]);
      float mx = fmaxf(t16[0], __shfl_xor(t16[0], 32));

      // ---- defer-max (T13): rescale only when max grows past THR ----
      if (__any(mx > m_r + 8.0f)) {
        float mn = fmaxf(m_r, mx);
        float alpha = exp2f(m_r - mn);
        m_r = mn; l_r *= alpha;
#pragma unroll
        for (int dt = 0; dt < 4; dt++)
#pragma unroll
          for (int r = 0; r < 16; r++) accO[dt][r] *= alpha;
      }

      // ---- exp + row sum ----
#pragma unroll
      for (int i = 0; i < 32; i++) p[i] = exp2f(p[i] - m_r);
      float s16[16];
#pragma unroll
      for (int i = 0; i < 16; i++) s16[i] = p[i] + p[i + 16];
#pragma unroll
      for (int st = 8; st >= 1; st >>= 1)
#pragma unroll
        for (int i = 0; i < st; i++) s16[i] += s16[i + st];
      l_r += s16[0] + __shfl_xor(s16[0], 32);

      // ---- pack P to bf16 pairs: pk[octet][c] = (kv=8o+4hi+2c, +1) ----
      unsigned pk[8][2];
#pragma unroll
      for (int o = 0; o < 8; o++)
#pragma unroll
        for (int c = 0; c < 2; c++) {
          float lo = p[(o >> 2) * 16 + (o & 3) * 4 + 2 * c];
          float hi_ = p[(o >> 2) * 16 + (o & 3) * 4 + 2 * c + 1];
          asm("v_cvt_pk_bf16_f32 %0, %1, %2" : "=v"(pk[o][c]) : "v"(lo), "v"(hi_));
        }

      // ---- PV: O^T += V^T P^T ; B-frag(ks) = kv 16ks+8hi+0..7 via half-exchange ----
      const char* Vb = (const char*)V_l[cur] + l31 * 128;
#pragma unroll
      for (int ks = 0; ks < 4; ks++) {
        unsigned e0 = pk[2 * ks][0], e1 = pk[2 * ks][1];
        unsigned o0 = pk[2 * ks + 1][0], o1 = pk[2 * ks + 1][1];
        unsigned xe0 = (unsigned)__shfl_xor((int)e0, 32);
        unsigned xe1 = (unsigned)__shfl_xor((int)e1, 32);
        unsigned xo0 = (unsigned)__shfl_xor((int)o0, 32);
        unsigned xo1 = (unsigned)__shfl_xor((int)o1, 32);
        uint4v pw;
        pw.x = hi ? xo0 : e0;   // kv 16ks+8hi+{0,1}
        pw.y = hi ? xo1 : e1;   // +{2,3}
        pw.z = hi ? o0 : xe0;   // +{4,5}
        pw.w = hi ? o1 : xe1;   // +{6,7}
        short8 pb = __builtin_bit_cast(short8, pw);
        int sl = ((2 * ks + hi) ^ r7) * 16;
#pragma unroll
        for (int dt = 0; dt < 4; dt++) {
          short8 vf = *(const short8*)(Vb + dt * 32 * 128 + sl);
          accO[dt] = __builtin_amdgcn_mfma_f32_32x32x16_bf16(vf, pb, accO[dt], 0, 0, 0);
        }
      }
    }

    // ---- epilogue: O = accO^T / l ; write [t][h*128+d] ----
    float inv = 1.0f / l_r;
#pragma unroll
    for (int dt = 0; dt < 4; dt++)
#pragma unroll
      for (int r = 0; r < 16; r++) {
        int d = 32 * dt + (r & 3) + 8 * (r >> 2) + 4 * hi;
        ao[(size_t)q_row * HDIM + h * HD + d] = f2bf(accO[dt][r] * inv);
      }
  }
}

// ---------------- launch ----------------
extern "C" void kernel_launch(void* const* d_in, const int* in_sizes, int n_in,
                              void* d_out, int out_size, void* d_ws, size_t ws_size,
                              hipStream_t stream) {
  const float* x      = (const float*)d_in[0];
  const float* ve     = (const float*)d_in[1];
  const float* lam    = (const float*)d_in[2];
  const float* qkv_w  = (const float*)d_in[3];
  const float* proj_w = (const float*)d_in[4];
  float* out = (float*)d_out;

  char* p = (char*)d_ws;
  float* cosT = (float*)p;            p += (size_t)T_SEQ * 64 * 4;
  float* sinT = (float*)p;            p += (size_t)T_SEQ * 64 * 4;
  unsigned short* xb   = (unsigned short*)p; p += (size_t)T_SEQ * DIM * 2;
  unsigned short* wqb  = (unsigned short*)p; p += (size_t)3 * HDIM * DIM * 2;
  unsigned short* pwb  = (unsigned short*)p; p += (size_t)DIM * HDIM * 2;
  unsigned short* qkvb = (unsigned short*)p; p += (size_t)3 * NH * T_SEQ * HD * 2;
  unsigned short* vtb  = (unsigned short*)p; p += (size_t)NH * HD * T_SEQ * 2;
  unsigned short* aob  = (unsigned short*)p; p += (size_t)T_SEQ * HDIM * 2;

  cvt_f32_bf16<<<(T_SEQ * DIM / 4 + 255) / 256, 256, 0, stream>>>(x, xb, T_SEQ * DIM / 4);
  cvt_f32_bf16<<<(3 * HDIM * DIM / 4 + 255) / 256, 256, 0, stream>>>(qkv_w, wqb, 3 * HDIM * DIM / 4);
  cvt_f32_bf16<<<(DIM * HDIM / 4 + 255) / 256, 256, 0, stream>>>(proj_w, pwb, DIM * HDIM / 4);
  rope_tables<<<(T_SEQ * 64 + 255) / 256, 256, 0, stream>>>(cosT, sinT);

  gemm_bt<0><<<dim3(T_SEQ / 128, 3 * HDIM / 128), 256, 0, stream>>>(xb, wqb, DIM, qkvb, nullptr, 3 * HDIM);
  norm_rope<<<2 * NH * T_SEQ / 4, 256, 0, stream>>>(qkvb, cosT, sinT);
  vmix_transpose<<<dim3(T_SEQ / 64, HD / 64, NH), 256, 0, stream>>>(
      qkvb + (size_t)2 * NH * T_SEQ * HD, ve, lam, vtb);
  attn_fwd<<<dim3(16, NH), 256, 0, stream>>>(qkvb, qkvb + (size_t)NH * T_SEQ * HD, vtb, aob);
  gemm_bt<1><<<dim3(T_SEQ / 128, HDIM / 128), 256, 0, stream>>>(aob, pwb, HDIM, nullptr, out, HDIM);
}

// Round 4
// 403.205 us; speedup vs baseline: 2.1463x; 1.0296x over previous
//
#include <hip/hip_runtime.h>
#include <cstdint>
#include <cstddef>

// ---------------- constants ----------------
constexpr int T_SEQ = 4096;
constexpr int NH    = 16;
constexpr int HD    = 128;
constexpr int DIM   = 2048;
constexpr int HDIM  = 2048;   // NH*HD

typedef __attribute__((ext_vector_type(8)))  short  short8;
typedef __attribute__((ext_vector_type(4)))  float  f32x4;
typedef __attribute__((ext_vector_type(16))) float  f32x16;
typedef __attribute__((ext_vector_type(8)))  unsigned short u16x8;
typedef __attribute__((ext_vector_type(4)))  unsigned short u16x4;
typedef __attribute__((ext_vector_type(4)))  unsigned uint4v;

__device__ __forceinline__ unsigned short f2bf(float f) {
  unsigned u = __float_as_uint(f);
  return (unsigned short)((u + 0x7FFFu + ((u >> 16) & 1u)) >> 16);  // RNE
}
__device__ __forceinline__ float bf2f(unsigned short h) {
  return __uint_as_float(((unsigned)h) << 16);
}
__device__ __forceinline__ void gload_lds16(const void* g, void* l) {
  __builtin_amdgcn_global_load_lds((const __attribute__((address_space(1))) void*)g,
                                   (__attribute__((address_space(3))) void*)l, 16, 0, 0);
}

// ---------------- fp32 -> bf16 convert ----------------
__global__ __launch_bounds__(256) void cvt_f32_bf16(const float* __restrict__ in,
                                                    unsigned short* __restrict__ out, int n4) {
  int i = blockIdx.x * 256 + threadIdx.x;
  if (i < n4) {
    float4 v = ((const float4*)in)[i];
    u16x4 o; o.x = f2bf(v.x); o.y = f2bf(v.y); o.z = f2bf(v.z); o.w = f2bf(v.w);
    ((u16x4*)out)[i] = o;
  }
}

// ---------------- RoPE tables ----------------
__global__ __launch_bounds__(256) void rope_tables(float* __restrict__ cosT, float* __restrict__ sinT) {
  int idx = blockIdx.x * 256 + threadIdx.x;           // T_SEQ*64
  if (idx >= T_SEQ * 64) return;
  int t = idx >> 6, i = idx & 63;
  float ang = (i < 32) ? exp2f(-10.0f * (float)i / 31.0f) : 0.0f;  // (1/1024)^(i/31)
  float th = (float)t * ang;
  cosT[idx] = cosf(th);
  sinT[idx] = sinf(th);
}

// ---------------- GEMM: C = A * B^T  (A:[M][K] bf16, B:[N][K] bf16) ----------------
template <int MODE>
__global__ __launch_bounds__(256) void gemm_bt(const unsigned short* __restrict__ A,
                                               const unsigned short* __restrict__ B,
                                               int K, unsigned short* __restrict__ outb,
                                               float* __restrict__ outf, int N) {
  __shared__ unsigned short As[128 * 64];
  __shared__ unsigned short Bs[128 * 64];
  const int tid = threadIdx.x;
  const int w = tid >> 6, lane = tid & 63;
  const int wm = w >> 1, wn = w & 1;
  const int m0 = blockIdx.x * 128, n0 = blockIdx.y * 128;
  const int lr = lane >> 4, lc = lane & 15;
  const int srow = lane >> 3, scol = (lane & 7) * 8;   // staging: 8 rows x 64 cols per 1KB chunk

  f32x4 acc[4][4] = {};
  const int nkt = K >> 6;
  for (int kt = 0; kt < nkt; kt++) {
    __syncthreads();
    const int k0 = kt * 64;
#pragma unroll
    for (int i = 0; i < 4; i++) {
      int row = (w * 4 + i) * 8 + srow;
      gload_lds16(A + (size_t)(m0 + row) * K + k0 + scol, (char*)As + (w * 4 + i) * 1024);
      gload_lds16(B + (size_t)(n0 + row) * K + k0 + scol, (char*)Bs + (w * 4 + i) * 1024);
    }
    __syncthreads();
#pragma unroll
    for (int kk = 0; kk < 2; kk++) {
      short8 a[4], b[4];
#pragma unroll
      for (int mi = 0; mi < 4; mi++)
        a[mi] = *(const short8*)(As + (wm * 64 + mi * 16 + lc) * 64 + kk * 32 + lr * 8);
#pragma unroll
      for (int ni = 0; ni < 4; ni++)
        b[ni] = *(const short8*)(Bs + (wn * 64 + ni * 16 + lc) * 64 + kk * 32 + lr * 8);
#pragma unroll
      for (int mi = 0; mi < 4; mi++)
#pragma unroll
        for (int ni = 0; ni < 4; ni++)
          acc[mi][ni] = __builtin_amdgcn_mfma_f32_16x16x32_bf16(a[mi], b[ni], acc[mi][ni], 0, 0, 0);
    }
  }
#pragma unroll
  for (int mi = 0; mi < 4; mi++)
#pragma unroll
    for (int ni = 0; ni < 4; ni++)
#pragma unroll
      for (int r = 0; r < 4; r++) {
        int t = m0 + wm * 64 + mi * 16 + lr * 4 + r;
        int n = n0 + wn * 64 + ni * 16 + lc;
        float v = acc[mi][ni][r];
        if (MODE == 0) {
          int c = n >> 11, e = n & 2047, h = e >> 7, d = e & 127;
          outb[(((size_t)c * NH + h) * T_SEQ + t) * HD + d] = f2bf(v);
        } else {
          outf[(size_t)t * N + n] = v;
        }
      }
}

// ---------------- RMSNorm + RoPE (in-place on q,k; layout [c][h][t][d]) ----------------
__global__ __launch_bounds__(256) void norm_rope(unsigned short* __restrict__ qkvb,
                                                 const float* __restrict__ cosT,
                                                 const float* __restrict__ sinT) {
  int r = blockIdx.x * 4 + (threadIdx.x >> 6);   // row over [c][h][t], c in {0,1}
  int lane = threadIdx.x & 63;
  int t = r % T_SEQ;
  unsigned short* row = qkvb + (size_t)r * HD;
  float f1 = bf2f(row[lane]), f2 = bf2f(row[lane + 64]);
  float ss = f1 * f1 + f2 * f2;
#pragma unroll
  for (int off = 32; off; off >>= 1) ss += __shfl_xor(ss, off, 64);
  float rs = rsqrtf(ss * (1.0f / 128.0f) + 1e-6f);
  f1 *= rs; f2 *= rs;
  float c_ = cosT[t * 64 + lane], s_ = sinT[t * 64 + lane];
  row[lane]      = f2bf(f1 * c_ + f2 * s_);
  row[lane + 64] = f2bf(-f1 * s_ + f2 * c_);
}

// ---------------- v' = l0*v + l1*ve, transposed to v_t[h][d][t] ----------------
__global__ __launch_bounds__(256) void vmix_transpose(const unsigned short* __restrict__ vb,
                                                      const float* __restrict__ ve,
                                                      const float* __restrict__ lam,
                                                      unsigned short* __restrict__ vt) {
  __shared__ float tile[64][65];
  const int h = blockIdx.z, t0 = blockIdx.x * 64, d0 = blockIdx.y * 64;
  const float l0 = lam[0], l1 = lam[1];
  const int tid = threadIdx.x;
  const int tl = tid >> 4, dl4 = (tid & 15) * 4;
#pragma unroll
  for (int i = 0; i < 4; i++) {
    int t_local = tl + i * 16;
    int t = t0 + t_local;
    const unsigned short* vp = vb + ((size_t)h * T_SEQ + t) * HD + d0 + dl4;
    const float* vep = ve + (size_t)t * HDIM + h * HD + d0 + dl4;
    u16x4 vv = *(const u16x4*)vp;
    float4 vef = *(const float4*)vep;
    tile[t_local][dl4 + 0] = l0 * bf2f(vv.x) + l1 * vef.x;
    tile[t_local][dl4 + 1] = l0 * bf2f(vv.y) + l1 * vef.y;
    tile[t_local][dl4 + 2] = l0 * bf2f(vv.z) + l1 * vef.z;
    tile[t_local][dl4 + 3] = l0 * bf2f(vv.w) + l1 * vef.w;
  }
  __syncthreads();
#pragma unroll
  for (int i = 0; i < 2; i++) {
    int idx = tid + i * 256;
    int d_local = idx >> 3, tloc = (idx & 7) * 8;
    u16x8 o;
#pragma unroll
    for (int j = 0; j < 8; j++) o[j] = f2bf(tile[tloc + j][d_local]);
    *(u16x8*)(vt + ((size_t)h * HD + d0 + d_local) * T_SEQ + t0 + tloc) = o;
  }
}

// ---------------- flash attention (causal), swapped-operand 32x32x16 ----------------
// 8 warps / 512 threads. Warps 0-3 (group 0) process EVEN kv tiles, warps 4-7 (group 1)
// ODD kv tiles of the same QBLK=128 q-tile: each group gets exactly qt+1 tiles (balanced),
// each group has its own double-buffered K/V LDS (2x64KB = 128KB, 1 block/CU, 8 waves =
// 2 waves/SIMD for latency overlap). Swapped QK^T/PV keeps softmax per-lane in registers.
// At q-tile end: odd group writes unnormalized (accO, m, l) to LDS (d^q word swizzle,
// conflict-free); even group merges O=(Oe*2^(me-m)+Oo*2^(mo-m))/(le*2^(me-m)+lo*2^(mo-m)).
// Fully-masked odd edge tiles keep m=-1e30 -> annihilated by 2^(mo-m)=0 in the merge.
// Pairing (31-pr, pr): every block 33 tiles/group. Grid 256 1-D with XCD swizzle so all
// 16 blocks of a head share one XCD's L2 (K/V stream ~2MB/head vs 4MB L2/XCD).
__global__ __launch_bounds__(512, 1) void attn_fwd(const unsigned short* __restrict__ qb,
                                                   const unsigned short* __restrict__ kb,
                                                   const unsigned short* __restrict__ vt,
                                                   unsigned short* __restrict__ ao) {
  __shared__ __align__(16) char SMEM[131072];   // [group][ K 2x16KB | V 2x16KB ]
  const int bid = blockIdx.x;
  const int h  = (bid & 7) + ((bid >> 7) << 3);  // XCD swizzle: head h on XCD h%8
  const int pr = (bid >> 3) & 15;
  const int tid = threadIdx.x, w = tid >> 6, lane = tid & 63;
  const int g = w >> 2, wq = w & 3;
  const int l31 = lane & 31, hi = lane >> 5, r7 = l31 & 7;
  const unsigned short* qh = qb + (size_t)h * T_SEQ * HD;
  const unsigned short* kh = kb + (size_t)h * T_SEQ * HD;
  const unsigned short* vh = vt + (size_t)h * HD * T_SEQ;

  char* Kbase = SMEM + g * 65536;
  char* Vbase = SMEM + g * 65536 + 32768;

  const int kcrow = lane >> 4, kcol16 = lane & 15;   // K staging: 4 rows / 1KB chunk
  const int vcrow = lane >> 3, vslot0 = lane & 7;    // V staging: 8 rows / 1KB chunk

  auto STAGE = [&](int buf, int t) {                 // t = global kv tile index
#pragma unroll
    for (int i = 0; i < 4; i++) {
      int krow = (wq * 4 + i) * 4 + kcrow;
      int kcol = (kcol16 ^ (krow & 7)) * 8;          // pre-swizzled source (rule #21)
      gload_lds16(kh + (size_t)(t * 64 + krow) * HD + kcol,
                  Kbase + buf * 16384 + (wq * 4 + i) * 1024);
      int vrow = (wq * 4 + i) * 8 + vcrow;
      int vcol = (vslot0 ^ (vrow & 7)) * 8;
      gload_lds16(vh + (size_t)vrow * T_SEQ + t * 64 + vcol,
                  Vbase + buf * 16384 + (wq * 4 + i) * 1024);
    }
  };

  const float SCL2E = 0.088388347648318447f * 1.44269504f;  // 1/sqrt(128) * log2(e)

#pragma unroll 1
  for (int which = 0; which < 2; ++which) {
    const int qt = which ? pr : (31 - pr);     // heavy tile first
    const int ng = qt + 1;                     // tiles for THIS group (parity g)
    const int q_row = qt * 128 + wq * 32 + l31;

    short8 qf[8];                              // B-frag: Q[q_row][16dk + 8hi + 0..7]
#pragma unroll
    for (int dk = 0; dk < 8; dk++)
      qf[dk] = *(const short8*)(qh + (size_t)q_row * HD + dk * 16 + hi * 8);

    f32x16 accO[4] = {};                       // O^T: col=q, rows d (4 tiles of 32)
    float m_r = -1e30f, l_r = 0.0f;

    __syncthreads();                           // prev combine reads done
    STAGE(0, g);

#pragma unroll 1
    for (int it = 0; it < ng; it++) {
      const int t = 2 * it + g;                // this group's kv tile
      const int cur = it & 1;
      asm volatile("s_waitcnt vmcnt(0)" ::: "memory");  // own stage(cur) landed
      __syncthreads();
      if (it + 1 < ng) STAGE(cur ^ 1, t + 2);           // prefetch under compute

      // ---- S^T = K Q^T : 2 kv-subtiles x 8 d-steps ----
      f32x16 accS0 = {}, accS1 = {};
      const char* Kb = Kbase + cur * 16384 + l31 * 256;
      __builtin_amdgcn_s_setprio(1);
#pragma unroll
      for (int dk = 0; dk < 8; dk++) {
        int sl = ((2 * dk + hi) ^ r7) * 16;
        short8 k0 = *(const short8*)(Kb + sl);
        short8 k1 = *(const short8*)(Kb + 32 * 256 + sl);
        accS0 = __builtin_amdgcn_mfma_f32_32x32x16_bf16(k0, qf[dk], accS0, 0, 0, 0);
        accS1 = __builtin_amdgcn_mfma_f32_32x32x16_bf16(k1, qf[dk], accS1, 0, 0, 0);
      }
      __builtin_amdgcn_s_setprio(0);

      // ---- scale + causal mask; lane holds P[q_row][kv], kv = 64t+(r&3)+8(r>>2)+4hi ----
      float p[32];
      const bool need_mask = (t * 64 + 63) > (qt * 128 + wq * 32);
      if (need_mask) {
#pragma unroll
        for (int r = 0; r < 16; r++) {
          int kv0 = t * 64 + (r & 3) + 8 * (r >> 2) + 4 * hi;
          p[r]      = (kv0      > q_row) ? -1e30f : accS0[r] * SCL2E;
          p[16 + r] = (kv0 + 32 > q_row) ? -1e30f : accS1[r] * SCL2E;
        }
      } else {
#pragma unroll
        for (int r = 0; r < 16; r++) { p[r] = accS0[r] * SCL2E; p[16 + r] = accS1[r] * SCL2E; }
      }

      // ---- row max: in-register tree + one cross-half shfl ----
      float t16[16];
#pragma unroll
      for (int i = 0; i < 16; i++) t16[i] = fmaxf(p[i], p[i + 16]);
#pragma unroll
      for (int st = 8; st >= 1; st >>= 1)
#pragma unroll
        for (int i = 0; i < st; i++) t16[i] = fmaxf(t16[i], t16[i + st]);
      float mx = fmaxf(t16[0], __shfl_xor(t16[0], 32));

      // ---- defer-max (T13): rescale only when max grows past THR ----
      if (__any(mx > m_r + 8.0f)) {
        float mn = fmaxf(m_r, mx);
        float alpha = exp2f(m_r - mn);
        m_r = mn; l_r *= alpha;
#pragma unroll
        for (int dt = 0; dt < 4; dt++)
#pragma unroll
          for (int r = 0; r < 16; r++) accO[dt][r] *= alpha;
      }

      // ---- exp + row sum ----
#pragma unroll
      for (int i = 0; i < 32; i++) p[i] = exp2f(p[i] - m_r);
      float s16[16];
#pragma unroll
      for (int i = 0; i < 16; i++) s16[i] = p[i] + p[i + 16];
#pragma unroll
      for (int st = 8; st >= 1; st >>= 1)
#pragma unroll
        for (int i = 0; i < st; i++) s16[i] += s16[i + st];
      l_r += s16[0] + __shfl_xor(s16[0], 32);

      // ---- pack P to bf16 pairs ----
      unsigned pk[8][2];
#pragma unroll
      for (int o = 0; o < 8; o++)
#pragma unroll
        for (int c = 0; c < 2; c++) {
          float lo = p[(o >> 2) * 16 + (o & 3) * 4 + 2 * c];
          float hi_ = p[(o >> 2) * 16 + (o & 3) * 4 + 2 * c + 1];
          asm("v_cvt_pk_bf16_f32 %0, %1, %2" : "=v"(pk[o][c]) : "v"(lo), "v"(hi_));
        }

      // ---- PV: O^T += V^T P^T ; B-frag(ks) via half-exchange ----
      const char* Vb = Vbase + cur * 16384 + l31 * 128;
#pragma unroll
      for (int ks = 0; ks < 4; ks++) {
        unsigned e0 = pk[2 * ks][0], e1 = pk[2 * ks][1];
        unsigned o0 = pk[2 * ks + 1][0], o1 = pk[2 * ks + 1][1];
        unsigned xe0 = (unsigned)__shfl_xor((int)e0, 32);
        unsigned xe1 = (unsigned)__shfl_xor((int)e1, 32);
        unsigned xo0 = (unsigned)__shfl_xor((int)o0, 32);
        unsigned xo1 = (unsigned)__shfl_xor((int)o1, 32);
        uint4v pw;
        pw.x = hi ? xo0 : e0;
        pw.y = hi ? xo1 : e1;
        pw.z = hi ? o0 : xe0;
        pw.w = hi ? o1 : xe1;
        short8 pb = __builtin_bit_cast(short8, pw);
        int sl = ((2 * ks + hi) ^ r7) * 16;
        __builtin_amdgcn_s_setprio(1);
#pragma unroll
        for (int dt = 0; dt < 4; dt++) {
          short8 vf = *(const short8*)(Vb + dt * 32 * 128 + sl);
          accO[dt] = __builtin_amdgcn_mfma_f32_32x32x16_bf16(vf, pb, accO[dt], 0, 0, 0);
        }
        __builtin_amdgcn_s_setprio(0);
      }
    }

    // ---- combine even/odd partials, even group writes output ----
    __syncthreads();                                  // all compute done
    float* SM_acc = (float*)(SMEM + 65536);           // odd group's staging (dead now)
    float* SM_ml  = (float*)SMEM;                     // even group's staging (dead now)
    const int q_local = wq * 32 + l31;
    if (g == 1) {
#pragma unroll
      for (int dt = 0; dt < 4; dt++)
#pragma unroll
        for (int r = 0; r < 16; r++) {
          int d = 32 * dt + (r & 3) + 8 * (r >> 2) + 4 * hi;
          SM_acc[q_local * 128 + (d ^ l31)] = accO[dt][r];   // word-swz: conflict-free
        }
      if (hi == 0) { SM_ml[q_local * 2] = m_r; SM_ml[q_local * 2 + 1] = l_r; }
    }
    __syncthreads();                                  // partials visible
    if (g == 0) {
      float mo = SM_ml[q_local * 2], lo = SM_ml[q_local * 2 + 1];
      float m  = fmaxf(m_r, mo);
      float se = exp2f(m_r - m), so = exp2f(mo - m);
      float inv = 1.0f / (l_r * se + lo * so);
#pragma unroll
      for (int dt = 0; dt < 4; dt++)
#pragma unroll
        for (int q4 = 0; q4 < 4; q4++) {
          int dbase = 32 * dt + 8 * q4 + 4 * hi;
          u16x4 o;
#pragma unroll
          for (int j = 0; j < 4; j++) {
            int r = q4 * 4 + j, d = dbase + j;
            float vo = SM_acc[q_local * 128 + (d ^ l31)];
            o[j] = f2bf((accO[dt][r] * se + vo * so) * inv);
          }
          *(u16x4*)(ao + (size_t)q_row * HDIM + h * HD + dbase) = o;
        }
    }
  }
}

// ---------------- launch ----------------
extern "C" void kernel_launch(void* const* d_in, const int* in_sizes, int n_in,
                              void* d_out, int out_size, void* d_ws, size_t ws_size,
                              hipStream_t stream) {
  const float* x      = (const float*)d_in[0];
  const float* ve     = (const float*)d_in[1];
  const float* lam    = (const float*)d_in[2];
  const float* qkv_w  = (const float*)d_in[3];
  const float* proj_w = (const float*)d_in[4];
  float* out = (float*)d_out;

  char* p = (char*)d_ws;
  float* cosT = (float*)p;            p += (size_t)T_SEQ * 64 * 4;
  float* sinT = (float*)p;            p += (size_t)T_SEQ * 64 * 4;
  unsigned short* xb   = (unsigned short*)p; p += (size_t)T_SEQ * DIM * 2;
  unsigned short* wqb  = (unsigned short*)p; p += (size_t)3 * HDIM * DIM * 2;
  unsigned short* pwb  = (unsigned short*)p; p += (size_t)DIM * HDIM * 2;
  unsigned short* qkvb = (unsigned short*)p; p += (size_t)3 * NH * T_SEQ * HD * 2;
  unsigned short* vtb  = (unsigned short*)p; p += (size_t)NH * HD * T_SEQ * 2;
  unsigned short* aob  = (unsigned short*)p; p += (size_t)T_SEQ * HDIM * 2;

  cvt_f32_bf16<<<(T_SEQ * DIM / 4 + 255) / 256, 256, 0, stream>>>(x, xb, T_SEQ * DIM / 4);
  cvt_f32_bf16<<<(3 * HDIM * DIM / 4 + 255) / 256, 256, 0, stream>>>(qkv_w, wqb, 3 * HDIM * DIM / 4);
  cvt_f32_bf16<<<(DIM * HDIM / 4 + 255) / 256, 256, 0, stream>>>(proj_w, pwb, DIM * HDIM / 4);
  rope_tables<<<(T_SEQ * 64 + 255) / 256, 256, 0, stream>>>(cosT, sinT);

  gemm_bt<0><<<dim3(T_SEQ / 128, 3 * HDIM / 128), 256, 0, stream>>>(xb, wqb, DIM, qkvb, nullptr, 3 * HDIM);
  norm_rope<<<2 * NH * T_SEQ / 4, 256, 0, stream>>>(qkvb, cosT, sinT);
  vmix_transpose<<<dim3(T_SEQ / 64, HD / 64, NH), 256, 0, stream>>>(
      qkvb + (size_t)2 * NH * T_SEQ * HD, ve, lam, vtb);
  attn_fwd<<<256, 512, 0, stream>>>(qkvb, qkvb + (size_t)NH * T_SEQ * HD, vtb, aob);
  gemm_bt<1><<<dim3(T_SEQ / 128, HDIM / 128), 256, 0, stream>>>(aob, pwb, HDIM, nullptr, out, HDIM);
}

// Round 5
// 397.247 us; speedup vs baseline: 2.1785x; 1.0150x over previous
//
#include <hip/hip_runtime.h>
#include <cstdint>
#include <cstddef>

// ---------------- constants ----------------
constexpr int T_SEQ = 4096;
constexpr int NH    = 16;
constexpr int HD    = 128;
constexpr int DIM   = 2048;
constexpr int HDIM  = 2048;   // NH*HD

typedef __attribute__((ext_vector_type(8)))  short  short8;
typedef __attribute__((ext_vector_type(4)))  float  f32x4;
typedef __attribute__((ext_vector_type(16))) float  f32x16;
typedef __attribute__((ext_vector_type(8)))  unsigned short u16x8;
typedef __attribute__((ext_vector_type(4)))  unsigned short u16x4;
typedef __attribute__((ext_vector_type(4)))  unsigned uint4v;
typedef __attribute__((ext_vector_type(2)))  int int2v;

__device__ __forceinline__ unsigned short f2bf(float f) {
  unsigned u = __float_as_uint(f);
  return (unsigned short)((u + 0x7FFFu + ((u >> 16) & 1u)) >> 16);  // RNE
}
__device__ __forceinline__ float bf2f(unsigned short h) {
  return __uint_as_float(((unsigned)h) << 16);
}
__device__ __forceinline__ void gload_lds16(const void* g, void* l) {
  __builtin_amdgcn_global_load_lds((const __attribute__((address_space(1))) void*)g,
                                   (__attribute__((address_space(3))) void*)l, 16, 0, 0);
}
// (A',B') = permlane32_swap(A,B): A' = {A.lo, B.lo->hi? no: A'[l<32]=A[l], A'[l>=32]=B[l-32]},
//           B'[l<32]=A[l+32], B'[l>=32]=B[l].  VALU op — off the LDS pipe.
__device__ __forceinline__ int2v plswap(int a, int b) {
  return __builtin_amdgcn_permlane32_swap(a, b, false, false);
}

// ---------------- fp32 -> bf16 convert ----------------
__global__ __launch_bounds__(256) void cvt_f32_bf16(const float* __restrict__ in,
                                                    unsigned short* __restrict__ out, int n4) {
  int i = blockIdx.x * 256 + threadIdx.x;
  if (i < n4) {
    float4 v = ((const float4*)in)[i];
    u16x4 o; o.x = f2bf(v.x); o.y = f2bf(v.y); o.z = f2bf(v.z); o.w = f2bf(v.w);
    ((u16x4*)out)[i] = o;
  }
}

// ---------------- RoPE tables ----------------
__global__ __launch_bounds__(256) void rope_tables(float* __restrict__ cosT, float* __restrict__ sinT) {
  int idx = blockIdx.x * 256 + threadIdx.x;           // T_SEQ*64
  if (idx >= T_SEQ * 64) return;
  int t = idx >> 6, i = idx & 63;
  float ang = (i < 32) ? exp2f(-10.0f * (float)i / 31.0f) : 0.0f;  // (1/1024)^(i/31)
  float th = (float)t * ang;
  cosT[idx] = cosf(th);
  sinT[idx] = sinf(th);
}

// ---------------- GEMM: C = A * B^T  (A:[M][K] bf16, B:[N][K] bf16) ----------------
template <int MODE>
__global__ __launch_bounds__(256) void gemm_bt(const unsigned short* __restrict__ A,
                                               const unsigned short* __restrict__ B,
                                               int K, unsigned short* __restrict__ outb,
                                               float* __restrict__ outf, int N) {
  __shared__ unsigned short As[128 * 64];
  __shared__ unsigned short Bs[128 * 64];
  const int tid = threadIdx.x;
  const int w = tid >> 6, lane = tid & 63;
  const int wm = w >> 1, wn = w & 1;
  const int m0 = blockIdx.x * 128, n0 = blockIdx.y * 128;
  const int lr = lane >> 4, lc = lane & 15;
  const int srow = lane >> 3, scol = (lane & 7) * 8;   // staging: 8 rows x 64 cols per 1KB chunk

  f32x4 acc[4][4] = {};
  const int nkt = K >> 6;
  for (int kt = 0; kt < nkt; kt++) {
    __syncthreads();
    const int k0 = kt * 64;
#pragma unroll
    for (int i = 0; i < 4; i++) {
      int row = (w * 4 + i) * 8 + srow;
      gload_lds16(A + (size_t)(m0 + row) * K + k0 + scol, (char*)As + (w * 4 + i) * 1024);
      gload_lds16(B + (size_t)(n0 + row) * K + k0 + scol, (char*)Bs + (w * 4 + i) * 1024);
    }
    __syncthreads();
#pragma unroll
    for (int kk = 0; kk < 2; kk++) {
      short8 a[4], b[4];
#pragma unroll
      for (int mi = 0; mi < 4; mi++)
        a[mi] = *(const short8*)(As + (wm * 64 + mi * 16 + lc) * 64 + kk * 32 + lr * 8);
#pragma unroll
      for (int ni = 0; ni < 4; ni++)
        b[ni] = *(const short8*)(Bs + (wn * 64 + ni * 16 + lc) * 64 + kk * 32 + lr * 8);
#pragma unroll
      for (int mi = 0; mi < 4; mi++)
#pragma unroll
        for (int ni = 0; ni < 4; ni++)
          acc[mi][ni] = __builtin_amdgcn_mfma_f32_16x16x32_bf16(a[mi], b[ni], acc[mi][ni], 0, 0, 0);
    }
  }
#pragma unroll
  for (int mi = 0; mi < 4; mi++)
#pragma unroll
    for (int ni = 0; ni < 4; ni++)
#pragma unroll
      for (int r = 0; r < 4; r++) {
        int t = m0 + wm * 64 + mi * 16 + lr * 4 + r;
        int n = n0 + wn * 64 + ni * 16 + lc;
        float v = acc[mi][ni][r];
        if (MODE == 0) {
          int c = n >> 11, e = n & 2047, h = e >> 7, d = e & 127;
          outb[(((size_t)c * NH + h) * T_SEQ + t) * HD + d] = f2bf(v);
        } else {
          outf[(size_t)t * N + n] = v;
        }
      }
}

// ---------------- RMSNorm + RoPE (in-place on q,k; layout [c][h][t][d]) ----------------
__global__ __launch_bounds__(256) void norm_rope(unsigned short* __restrict__ qkvb,
                                                 const float* __restrict__ cosT,
                                                 const float* __restrict__ sinT) {
  int r = blockIdx.x * 4 + (threadIdx.x >> 6);   // row over [c][h][t], c in {0,1}
  int lane = threadIdx.x & 63;
  int t = r % T_SEQ;
  unsigned short* row = qkvb + (size_t)r * HD;
  float f1 = bf2f(row[lane]), f2 = bf2f(row[lane + 64]);
  float ss = f1 * f1 + f2 * f2;
#pragma unroll
  for (int off = 32; off; off >>= 1) ss += __shfl_xor(ss, off, 64);
  float rs = rsqrtf(ss * (1.0f / 128.0f) + 1e-6f);
  f1 *= rs; f2 *= rs;
  float c_ = cosT[t * 64 + lane], s_ = sinT[t * 64 + lane];
  row[lane]      = f2bf(f1 * c_ + f2 * s_);
  row[lane + 64] = f2bf(-f1 * s_ + f2 * c_);
}

// ---------------- v' = l0*v + l1*ve, transposed to v_t[h][d][t] ----------------
__global__ __launch_bounds__(256) void vmix_transpose(const unsigned short* __restrict__ vb,
                                                      const float* __restrict__ ve,
                                                      const float* __restrict__ lam,
                                                      unsigned short* __restrict__ vt) {
  __shared__ float tile[64][65];
  const int h = blockIdx.z, t0 = blockIdx.x * 64, d0 = blockIdx.y * 64;
  const float l0 = lam[0], l1 = lam[1];
  const int tid = threadIdx.x;
  const int tl = tid >> 4, dl4 = (tid & 15) * 4;
#pragma unroll
  for (int i = 0; i < 4; i++) {
    int t_local = tl + i * 16;
    int t = t0 + t_local;
    const unsigned short* vp = vb + ((size_t)h * T_SEQ + t) * HD + d0 + dl4;
    const float* vep = ve + (size_t)t * HDIM + h * HD + d0 + dl4;
    u16x4 vv = *(const u16x4*)vp;
    float4 vef = *(const float4*)vep;
    tile[t_local][dl4 + 0] = l0 * bf2f(vv.x) + l1 * vef.x;
    tile[t_local][dl4 + 1] = l0 * bf2f(vv.y) + l1 * vef.y;
    tile[t_local][dl4 + 2] = l0 * bf2f(vv.z) + l1 * vef.z;
    tile[t_local][dl4 + 3] = l0 * bf2f(vv.w) + l1 * vef.w;
  }
  __syncthreads();
#pragma unroll
  for (int i = 0; i < 2; i++) {
    int idx = tid + i * 256;
    int d_local = idx >> 3, tloc = (idx & 7) * 8;
    u16x8 o;
#pragma unroll
    for (int j = 0; j < 8; j++) o[j] = f2bf(tile[tloc + j][d_local]);
    *(u16x8*)(vt + ((size_t)h * HD + d0 + d_local) * T_SEQ + t0 + tloc) = o;
  }
}

// ---------------- flash attention (causal), swapped-operand 32x32x16 ----------------
// 8 warps / 512 threads; kv-parity split (warps 0-3 even tiles, 4-7 odd) with LDS merge.
// __launch_bounds__(512, 2): per-SIMD VGPR pool = 512 -> 2 waves/SIMD allows 256 VGPR/wave
// (128-cap caused ~28MB of scratch spills in R4). permlane32_swap (VALU) replaces
// ds_bpermute shfls for all cross-half exchanges -- off the contended LDS pipe.
__global__ __launch_bounds__(512, 2) void attn_fwd(const unsigned short* __restrict__ qb,
                                                   const unsigned short* __restrict__ kb,
                                                   const unsigned short* __restrict__ vt,
                                                   unsigned short* __restrict__ ao) {
  __shared__ __align__(16) char SMEM[131072];   // [group][ K 2x16KB | V 2x16KB ]
  const int bid = blockIdx.x;
  const int h  = (bid & 7) + ((bid >> 7) << 3);  // XCD swizzle: head h on XCD h%8
  const int pr = (bid >> 3) & 15;
  const int tid = threadIdx.x, w = tid >> 6, lane = tid & 63;
  const int g = w >> 2, wq = w & 3;
  const int l31 = lane & 31, hi = lane >> 5, r7 = l31 & 7;
  const unsigned short* qh = qb + (size_t)h * T_SEQ * HD;
  const unsigned short* kh = kb + (size_t)h * T_SEQ * HD;
  const unsigned short* vh = vt + (size_t)h * HD * T_SEQ;

  char* Kbase = SMEM + g * 65536;
  char* Vbase = SMEM + g * 65536 + 32768;

  const int kcrow = lane >> 4, kcol16 = lane & 15;   // K staging: 4 rows / 1KB chunk
  const int vcrow = lane >> 3, vslot0 = lane & 7;    // V staging: 8 rows / 1KB chunk

  auto STAGE = [&](int buf, int t) {                 // t = global kv tile index
#pragma unroll
    for (int i = 0; i < 4; i++) {
      int krow = (wq * 4 + i) * 4 + kcrow;
      int kcol = (kcol16 ^ (krow & 7)) * 8;          // pre-swizzled source (rule #21)
      gload_lds16(kh + (size_t)(t * 64 + krow) * HD + kcol,
                  Kbase + buf * 16384 + (wq * 4 + i) * 1024);
      int vrow = (wq * 4 + i) * 8 + vcrow;
      int vcol = (vslot0 ^ (vrow & 7)) * 8;
      gload_lds16(vh + (size_t)vrow * T_SEQ + t * 64 + vcol,
                  Vbase + buf * 16384 + (wq * 4 + i) * 1024);
    }
  };

  const float SCL2E = 0.088388347648318447f * 1.44269504f;  // 1/sqrt(128) * log2(e)

#pragma unroll 1
  for (int which = 0; which < 2; ++which) {
    const int qt = which ? pr : (31 - pr);     // heavy tile first
    const int ng = qt + 1;                     // tiles for THIS group (parity g)
    const int q_row = qt * 128 + wq * 32 + l31;

    short8 qf[8];                              // B-frag: Q[q_row][16dk + 8hi + 0..7]
#pragma unroll
    for (int dk = 0; dk < 8; dk++)
      qf[dk] = *(const short8*)(qh + (size_t)q_row * HD + dk * 16 + hi * 8);

    f32x16 accO[4] = {};                       // O^T: col=q, rows d (4 tiles of 32)
    float m_r = -1e30f, l_r = 0.0f;

    __syncthreads();                           // prev combine reads done
    STAGE(0, g);

#pragma unroll 1
    for (int it = 0; it < ng; it++) {
      const int t = 2 * it + g;                // this group's kv tile
      const int cur = it & 1;
      asm volatile("s_waitcnt vmcnt(0)" ::: "memory");  // own stage(cur) landed
      __syncthreads();
      if (it + 1 < ng) STAGE(cur ^ 1, t + 2);           // prefetch under compute

      // ---- S^T = K Q^T : 2 kv-subtiles x 8 d-steps ----
      f32x16 accS0 = {}, accS1 = {};
      const char* Kb = Kbase + cur * 16384 + l31 * 256;
      __builtin_amdgcn_s_setprio(1);
#pragma unroll
      for (int dk = 0; dk < 8; dk++) {
        int sl = ((2 * dk + hi) ^ r7) * 16;
        short8 k0 = *(const short8*)(Kb + sl);
        short8 k1 = *(const short8*)(Kb + 32 * 256 + sl);
        accS0 = __builtin_amdgcn_mfma_f32_32x32x16_bf16(k0, qf[dk], accS0, 0, 0, 0);
        accS1 = __builtin_amdgcn_mfma_f32_32x32x16_bf16(k1, qf[dk], accS1, 0, 0, 0);
      }
      __builtin_amdgcn_s_setprio(0);

      // ---- scale + causal mask; lane holds P[q_row][kv], kv = 64t+(r&3)+8(r>>2)+4hi ----
      float p[32];
      const bool need_mask = (t * 64 + 63) > (qt * 128 + wq * 32);
      if (need_mask) {
#pragma unroll
        for (int r = 0; r < 16; r++) {
          int kv0 = t * 64 + (r & 3) + 8 * (r >> 2) + 4 * hi;
          p[r]      = (kv0      > q_row) ? -1e30f : accS0[r] * SCL2E;
          p[16 + r] = (kv0 + 32 > q_row) ? -1e30f : accS1[r] * SCL2E;
        }
      } else {
#pragma unroll
        for (int r = 0; r < 16; r++) { p[r] = accS0[r] * SCL2E; p[16 + r] = accS1[r] * SCL2E; }
      }

      // ---- row max: in-register tree + one cross-half permlane ----
      float t16[16];
#pragma unroll
      for (int i = 0; i < 16; i++) t16[i] = fmaxf(p[i], p[i + 16]);
#pragma unroll
      for (int st = 8; st >= 1; st >>= 1)
#pragma unroll
        for (int i = 0; i < st; i++) t16[i] = fmaxf(t16[i], t16[i + st]);
      int2v mr_ = plswap(__float_as_int(t16[0]), __float_as_int(t16[0]));
      float mx = fmaxf(t16[0], __int_as_float(hi ? mr_.x : mr_.y));

      // ---- defer-max (T13): rescale only when max grows past THR ----
      if (__any(mx > m_r + 8.0f)) {
        float mn = fmaxf(m_r, mx);
        float alpha = exp2f(m_r - mn);
        m_r = mn; l_r *= alpha;
#pragma unroll
        for (int dt = 0; dt < 4; dt++)
#pragma unroll
          for (int r = 0; r < 16; r++) accO[dt][r] *= alpha;
      }

      // ---- exp + row sum ----
#pragma unroll
      for (int i = 0; i < 32; i++) p[i] = exp2f(p[i] - m_r);
      float s16[16];
#pragma unroll
      for (int i = 0; i < 16; i++) s16[i] = p[i] + p[i + 16];
#pragma unroll
      for (int st = 8; st >= 1; st >>= 1)
#pragma unroll
        for (int i = 0; i < st; i++) s16[i] += s16[i + st];
      int2v sr_ = plswap(__float_as_int(s16[0]), __float_as_int(s16[0]));
      l_r += s16[0] + __int_as_float(hi ? sr_.x : sr_.y);

      // ---- pack P to bf16 pairs: pk[octet][c] = (kv=8o+4hi+2c, +1) ----
      unsigned pk[8][2];
#pragma unroll
      for (int o = 0; o < 8; o++)
#pragma unroll
        for (int c = 0; c < 2; c++) {
          float lo = p[(o >> 2) * 16 + (o & 3) * 4 + 2 * c];
          float hi_ = p[(o >> 2) * 16 + (o & 3) * 4 + 2 * c + 1];
          asm("v_cvt_pk_bf16_f32 %0, %1, %2" : "=v"(pk[o][c]) : "v"(lo), "v"(hi_));
        }

      // ---- PV: O^T += V^T P^T ; B-frag(ks) via permlane32_swap (VALU, dual-output) ----
      const char* Vb = Vbase + cur * 16384 + l31 * 128;
#pragma unroll
      for (int ks = 0; ks < 4; ks++) {
        // pw.x,pw.z = swap(e0,o0); pw.y,pw.w = swap(e1,o1)
        int2v s0 = plswap((int)pk[2 * ks][0], (int)pk[2 * ks + 1][0]);
        int2v s1 = plswap((int)pk[2 * ks][1], (int)pk[2 * ks + 1][1]);
        uint4v pw;
        pw.x = (unsigned)s0.x;   // kv 16ks+8hi+{0,1}
        pw.y = (unsigned)s1.x;   // +{2,3}
        pw.z = (unsigned)s0.y;   // +{4,5}
        pw.w = (unsigned)s1.y;   // +{6,7}
        short8 pb = __builtin_bit_cast(short8, pw);
        int sl = ((2 * ks + hi) ^ r7) * 16;
        __builtin_amdgcn_s_setprio(1);
#pragma unroll
        for (int dt = 0; dt < 4; dt++) {
          short8 vf = *(const short8*)(Vb + dt * 32 * 128 + sl);
          accO[dt] = __builtin_amdgcn_mfma_f32_32x32x16_bf16(vf, pb, accO[dt], 0, 0, 0);
        }
        __builtin_amdgcn_s_setprio(0);
      }
    }

    // ---- combine even/odd partials, even group writes output ----
    __syncthreads();                                  // all compute done
    float* SM_acc = (float*)(SMEM + 65536);           // odd group's staging (dead now)
    float* SM_ml  = (float*)SMEM;                     // even group's staging (dead now)
    const int q_local = wq * 32 + l31;
    if (g == 1) {
#pragma unroll
      for (int dt = 0; dt < 4; dt++)
#pragma unroll
        for (int r = 0; r < 16; r++) {
          int d = 32 * dt + (r & 3) + 8 * (r >> 2) + 4 * hi;
          SM_acc[q_local * 128 + (d ^ l31)] = accO[dt][r];   // word-swz: conflict-free
        }
      if (hi == 0) { SM_ml[q_local * 2] = m_r; SM_ml[q_local * 2 + 1] = l_r; }
    }
    __syncthreads();                                  // partials visible
    if (g == 0) {
      float mo = SM_ml[q_local * 2], lo = SM_ml[q_local * 2 + 1];
      float m  = fmaxf(m_r, mo);
      float se = exp2f(m_r - m), so = exp2f(mo - m);
      float inv = 1.0f / (l_r * se + lo * so);
#pragma unroll
      for (int dt = 0; dt < 4; dt++)
#pragma unroll
        for (int q4 = 0; q4 < 4; q4++) {
          int dbase = 32 * dt + 8 * q4 + 4 * hi;
          u16x4 o;
#pragma unroll
          for (int j = 0; j < 4; j++) {
            int r = q4 * 4 + j, d = dbase + j;
            float vo = SM_acc[q_local * 128 + (d ^ l31)];
            o[j] = f2bf((accO[dt][r] * se + vo * so) * inv);
          }
          *(u16x4*)(ao + (size_t)q_row * HDIM + h * HD + dbase) = o;
        }
    }
  }
}

// ---------------- launch ----------------
extern "C" void kernel_launch(void* const* d_in, const int* in_sizes, int n_in,
                              void* d_out, int out_size, void* d_ws, size_t ws_size,
                              hipStream_t stream) {
  const float* x      = (const float*)d_in[0];
  const float* ve     = (const float*)d_in[1];
  const float* lam    = (const float*)d_in[2];
  const float* qkv_w  = (const float*)d_in[3];
  const float* proj_w = (const float*)d_in[4];
  float* out = (float*)d_out;

  char* p = (char*)d_ws;
  float* cosT = (float*)p;            p += (size_t)T_SEQ * 64 * 4;
  float* sinT = (float*)p;            p += (size_t)T_SEQ * 64 * 4;
  unsigned short* xb   = (unsigned short*)p; p += (size_t)T_SEQ * DIM * 2;
  unsigned short* wqb  = (unsigned short*)p; p += (size_t)3 * HDIM * DIM * 2;
  unsigned short* pwb  = (unsigned short*)p; p += (size_t)DIM * HDIM * 2;
  unsigned short* qkvb = (unsigned short*)p; p += (size_t)3 * NH * T_SEQ * HD * 2;
  unsigned short* vtb  = (unsigned short*)p; p += (size_t)NH * HD * T_SEQ * 2;
  unsigned short* aob  = (unsigned short*)p; p += (size_t)T_SEQ * HDIM * 2;

  cvt_f32_bf16<<<(T_SEQ * DIM / 4 + 255) / 256, 256, 0, stream>>>(x, xb, T_SEQ * DIM / 4);
  cvt_f32_bf16<<<(3 * HDIM * DIM / 4 + 255) / 256, 256, 0, stream>>>(qkv_w, wqb, 3 * HDIM * DIM / 4);
  cvt_f32_bf16<<<(DIM * HDIM / 4 + 255) / 256, 256, 0, stream>>>(proj_w, pwb, DIM * HDIM / 4);
  rope_tables<<<(T_SEQ * 64 + 255) / 256, 256, 0, stream>>>(cosT, sinT);

  gemm_bt<0><<<dim3(T_SEQ / 128, 3 * HDIM / 128), 256, 0, stream>>>(xb, wqb, DIM, qkvb, nullptr, 3 * HDIM);
  norm_rope<<<2 * NH * T_SEQ / 4, 256, 0, stream>>>(qkvb, cosT, sinT);
  vmix_transpose<<<dim3(T_SEQ / 64, HD / 64, NH), 256, 0, stream>>>(
      qkvb + (size_t)2 * NH * T_SEQ * HD, ve, lam, vtb);
  attn_fwd<<<256, 512, 0, stream>>>(qkvb, qkvb + (size_t)NH * T_SEQ * HD, vtb, aob);
  gemm_bt<1><<<dim3(T_SEQ / 128, HDIM / 128), 256, 0, stream>>>(aob, pwb, HDIM, nullptr, out, HDIM);
}

// Round 6
// 383.067 us; speedup vs baseline: 2.2591x; 1.0370x over previous
//
#include <hip/hip_runtime.h>
#include <cstdint>
#include <cstddef>

// ---------------- constants ----------------
constexpr int T_SEQ = 4096;
constexpr int NH    = 16;
constexpr int HD    = 128;
constexpr int DIM   = 2048;
constexpr int HDIM  = 2048;   // NH*HD

typedef __attribute__((ext_vector_type(8)))  short  short8;
typedef __attribute__((ext_vector_type(4)))  float  f32x4;
typedef __attribute__((ext_vector_type(16))) float  f32x16;
typedef __attribute__((ext_vector_type(8)))  unsigned short u16x8;
typedef __attribute__((ext_vector_type(4)))  unsigned short u16x4;
typedef __attribute__((ext_vector_type(4)))  unsigned uint4v;
typedef __attribute__((ext_vector_type(2)))  int int2v;

__device__ __forceinline__ unsigned short f2bf(float f) {
  unsigned u = __float_as_uint(f);
  return (unsigned short)((u + 0x7FFFu + ((u >> 16) & 1u)) >> 16);  // RNE
}
__device__ __forceinline__ float bf2f(unsigned short h) {
  return __uint_as_float(((unsigned)h) << 16);
}
__device__ __forceinline__ void gload_lds16(const void* g, void* l) {
  __builtin_amdgcn_global_load_lds((const __attribute__((address_space(1))) void*)g,
                                   (__attribute__((address_space(3))) void*)l, 16, 0, 0);
}
__device__ __forceinline__ int2v plswap(int a, int b) {
  return __builtin_amdgcn_permlane32_swap(a, b, false, false);
}

// ---------------- fp32 -> bf16 convert ----------------
__global__ __launch_bounds__(256) void cvt_f32_bf16(const float* __restrict__ in,
                                                    unsigned short* __restrict__ out, int n4) {
  int i = blockIdx.x * 256 + threadIdx.x;
  if (i < n4) {
    float4 v = ((const float4*)in)[i];
    u16x4 o; o.x = f2bf(v.x); o.y = f2bf(v.y); o.z = f2bf(v.z); o.w = f2bf(v.w);
    ((u16x4*)out)[i] = o;
  }
}

// ---------------- RoPE tables ----------------
__global__ __launch_bounds__(256) void rope_tables(float* __restrict__ cosT, float* __restrict__ sinT) {
  int idx = blockIdx.x * 256 + threadIdx.x;           // T_SEQ*64
  if (idx >= T_SEQ * 64) return;
  int t = idx >> 6, i = idx & 63;
  float ang = (i < 32) ? exp2f(-10.0f * (float)i / 31.0f) : 0.0f;  // (1/1024)^(i/31)
  float th = (float)t * ang;
  cosT[idx] = cosf(th);
  sinT[idx] = sinf(th);
}

// ---------------- GEMM: C = A * B^T  (A:[M][K] bf16, B:[N][K] bf16) ----------------
template <int MODE>
__global__ __launch_bounds__(256) void gemm_bt(const unsigned short* __restrict__ A,
                                               const unsigned short* __restrict__ B,
                                               int K, unsigned short* __restrict__ outb,
                                               float* __restrict__ outf, int N) {
  __shared__ unsigned short As[128 * 64];
  __shared__ unsigned short Bs[128 * 64];
  const int tid = threadIdx.x;
  const int w = tid >> 6, lane = tid & 63;
  const int wm = w >> 1, wn = w & 1;
  const int m0 = blockIdx.x * 128, n0 = blockIdx.y * 128;
  const int lr = lane >> 4, lc = lane & 15;
  const int srow = lane >> 3, scol = (lane & 7) * 8;   // staging: 8 rows x 64 cols per 1KB chunk

  f32x4 acc[4][4] = {};
  const int nkt = K >> 6;
  for (int kt = 0; kt < nkt; kt++) {
    __syncthreads();
    const int k0 = kt * 64;
#pragma unroll
    for (int i = 0; i < 4; i++) {
      int row = (w * 4 + i) * 8 + srow;
      gload_lds16(A + (size_t)(m0 + row) * K + k0 + scol, (char*)As + (w * 4 + i) * 1024);
      gload_lds16(B + (size_t)(n0 + row) * K + k0 + scol, (char*)Bs + (w * 4 + i) * 1024);
    }
    __syncthreads();
#pragma unroll
    for (int kk = 0; kk < 2; kk++) {
      short8 a[4], b[4];
#pragma unroll
      for (int mi = 0; mi < 4; mi++)
        a[mi] = *(const short8*)(As + (wm * 64 + mi * 16 + lc) * 64 + kk * 32 + lr * 8);
#pragma unroll
      for (int ni = 0; ni < 4; ni++)
        b[ni] = *(const short8*)(Bs + (wn * 64 + ni * 16 + lc) * 64 + kk * 32 + lr * 8);
#pragma unroll
      for (int mi = 0; mi < 4; mi++)
#pragma unroll
        for (int ni = 0; ni < 4; ni++)
          acc[mi][ni] = __builtin_amdgcn_mfma_f32_16x16x32_bf16(a[mi], b[ni], acc[mi][ni], 0, 0, 0);
    }
  }
#pragma unroll
  for (int mi = 0; mi < 4; mi++)
#pragma unroll
    for (int ni = 0; ni < 4; ni++)
#pragma unroll
      for (int r = 0; r < 4; r++) {
        int t = m0 + wm * 64 + mi * 16 + lr * 4 + r;
        int n = n0 + wn * 64 + ni * 16 + lc;
        float v = acc[mi][ni][r];
        if (MODE == 0) {
          int c = n >> 11, e = n & 2047, h = e >> 7, d = e & 127;
          outb[(((size_t)c * NH + h) * T_SEQ + t) * HD + d] = f2bf(v);
        } else {
          outf[(size_t)t * N + n] = v;
        }
      }
}

// ---------------- RMSNorm + RoPE (in-place on q,k; layout [c][h][t][d]) ----------------
__global__ __launch_bounds__(256) void norm_rope(unsigned short* __restrict__ qkvb,
                                                 const float* __restrict__ cosT,
                                                 const float* __restrict__ sinT) {
  int r = blockIdx.x * 4 + (threadIdx.x >> 6);   // row over [c][h][t], c in {0,1}
  int lane = threadIdx.x & 63;
  int t = r % T_SEQ;
  unsigned short* row = qkvb + (size_t)r * HD;
  float f1 = bf2f(row[lane]), f2 = bf2f(row[lane + 64]);
  float ss = f1 * f1 + f2 * f2;
#pragma unroll
  for (int off = 32; off; off >>= 1) ss += __shfl_xor(ss, off, 64);
  float rs = rsqrtf(ss * (1.0f / 128.0f) + 1e-6f);
  f1 *= rs; f2 *= rs;
  float c_ = cosT[t * 64 + lane], s_ = sinT[t * 64 + lane];
  row[lane]      = f2bf(f1 * c_ + f2 * s_);
  row[lane + 64] = f2bf(-f1 * s_ + f2 * c_);
}

// ---------------- v' = l0*v + l1*ve, transposed to v_t[h][d][t] ----------------
__global__ __launch_bounds__(256) void vmix_transpose(const unsigned short* __restrict__ vb,
                                                      const float* __restrict__ ve,
                                                      const float* __restrict__ lam,
                                                      unsigned short* __restrict__ vt) {
  __shared__ float tile[64][65];
  const int h = blockIdx.z, t0 = blockIdx.x * 64, d0 = blockIdx.y * 64;
  const float l0 = lam[0], l1 = lam[1];
  const int tid = threadIdx.x;
  const int tl = tid >> 4, dl4 = (tid & 15) * 4;
#pragma unroll
  for (int i = 0; i < 4; i++) {
    int t_local = tl + i * 16;
    int t = t0 + t_local;
    const unsigned short* vp = vb + ((size_t)h * T_SEQ + t) * HD + d0 + dl4;
    const float* vep = ve + (size_t)t * HDIM + h * HD + d0 + dl4;
    u16x4 vv = *(const u16x4*)vp;
    float4 vef = *(const float4*)vep;
    tile[t_local][dl4 + 0] = l0 * bf2f(vv.x) + l1 * vef.x;
    tile[t_local][dl4 + 1] = l0 * bf2f(vv.y) + l1 * vef.y;
    tile[t_local][dl4 + 2] = l0 * bf2f(vv.z) + l1 * vef.z;
    tile[t_local][dl4 + 3] = l0 * bf2f(vv.w) + l1 * vef.w;
  }
  __syncthreads();
#pragma unroll
  for (int i = 0; i < 2; i++) {
    int idx = tid + i * 256;
    int d_local = idx >> 3, tloc = (idx & 7) * 8;
    u16x8 o;
#pragma unroll
    for (int j = 0; j < 8; j++) o[j] = f2bf(tile[tloc + j][d_local]);
    *(u16x8*)(vt + ((size_t)h * HD + d0 + d_local) * T_SEQ + t0 + tloc) = o;
  }
}

// ---------------- flash attention (causal), swapped-operand 32x32x16 ----------------
// 8 warps / 512 threads; kv-parity split (warps 0-3 even tiles, 4-7 odd) with LDS merge.
// amdgpu_waves_per_eu(2,2): truthful cap (LDS 128KB -> 1 block/CU -> 2 waves/EU) telling
// the allocator it may use the full 256-VGPR budget -> kill R4/R5's scratch spills.
// Per-iter sync is a GROUP-LOCAL monotonic LDS-counter barrier (4 waves), not
// __syncthreads(): the two parity groups drift phase so one group's softmax (VALU)
// overlaps the other's QK^T/PV (MFMA+LDS). Full block barriers only at q-tile start
// and the cross-group combine. Both groups run exactly ng=qt+1 iters -> equal barrier
// counts -> no deadlock.
__global__ __launch_bounds__(512)
__attribute__((amdgpu_waves_per_eu(2, 2)))
void attn_fwd(const unsigned short* __restrict__ qb,
              const unsigned short* __restrict__ kb,
              const unsigned short* __restrict__ vt,
              unsigned short* __restrict__ ao) {
  __shared__ __align__(16) char SMEM[131072];   // [group][ K 2x16KB | V 2x16KB ]
  __shared__ int gctr[2];                       // group-barrier monotonic counters
  const int bid = blockIdx.x;
  const int h  = (bid & 7) + ((bid >> 7) << 3);  // XCD swizzle: head h on XCD h%8
  const int pr = (bid >> 3) & 15;
  const int tid = threadIdx.x, w = tid >> 6, lane = tid & 63;
  const int g = w >> 2, wq = w & 3;
  const int l31 = lane & 31, hi = lane >> 5, r7 = l31 & 7;
  const unsigned short* qh = qb + (size_t)h * T_SEQ * HD;
  const unsigned short* kh = kb + (size_t)h * T_SEQ * HD;
  const unsigned short* vh = vt + (size_t)h * HD * T_SEQ;

  if (tid < 2) gctr[tid] = 0;
  __syncthreads();
  int bcnt = 0;
  auto GBAR = [&]() {   // group-local barrier: 4 waves of group g
    asm volatile("s_waitcnt lgkmcnt(0)" ::: "memory");
    ++bcnt;
    if (lane == 0)
      __hip_atomic_fetch_add(&gctr[g], 1, __ATOMIC_RELEASE, __HIP_MEMORY_SCOPE_WORKGROUP);
    while (__hip_atomic_load(&gctr[g], __ATOMIC_ACQUIRE, __HIP_MEMORY_SCOPE_WORKGROUP) < 4 * bcnt)
      __builtin_amdgcn_s_sleep(1);
  };

  char* Kbase = SMEM + g * 65536;
  char* Vbase = SMEM + g * 65536 + 32768;

  const int kcrow = lane >> 4, kcol16 = lane & 15;   // K staging: 4 rows / 1KB chunk
  const int vcrow = lane >> 3, vslot0 = lane & 7;    // V staging: 8 rows / 1KB chunk

  auto STAGE = [&](int buf, int t) {                 // t = global kv tile index
#pragma unroll
    for (int i = 0; i < 4; i++) {
      int krow = (wq * 4 + i) * 4 + kcrow;
      int kcol = (kcol16 ^ (krow & 7)) * 8;          // pre-swizzled source (rule #21)
      gload_lds16(kh + (size_t)(t * 64 + krow) * HD + kcol,
                  Kbase + buf * 16384 + (wq * 4 + i) * 1024);
      int vrow = (wq * 4 + i) * 8 + vcrow;
      int vcol = (vslot0 ^ (vrow & 7)) * 8;
      gload_lds16(vh + (size_t)vrow * T_SEQ + t * 64 + vcol,
                  Vbase + buf * 16384 + (wq * 4 + i) * 1024);
    }
  };

  const float SCL2E = 0.088388347648318447f * 1.44269504f;  // 1/sqrt(128) * log2(e)

#pragma unroll 1
  for (int which = 0; which < 2; ++which) {
    const int qt = which ? pr : (31 - pr);     // heavy tile first
    const int ng = qt + 1;                     // tiles for THIS group (parity g)
    const int q_row = qt * 128 + wq * 32 + l31;

    short8 qf[8];                              // B-frag: Q[q_row][16dk + 8hi + 0..7]
#pragma unroll
    for (int dk = 0; dk < 8; dk++)
      qf[dk] = *(const short8*)(qh + (size_t)q_row * HD + dk * 16 + hi * 8);

    f32x16 accO[4] = {};                       // O^T: col=q, rows d (4 tiles of 32)
    float m_r = -1e30f, l_r = 0.0f;

    __syncthreads();                           // prev combine reads done (cross-group)
    STAGE(0, g);

#pragma unroll 1
    for (int it = 0; it < ng; it++) {
      const int t = 2 * it + g;                // this group's kv tile
      const int cur = it & 1;
      asm volatile("s_waitcnt vmcnt(0)" ::: "memory");  // own stage(cur) landed
      GBAR();                                           // group's stage(cur) landed
      if (it + 1 < ng) STAGE(cur ^ 1, t + 2);           // prefetch under compute

      // ---- S^T = K Q^T : 2 kv-subtiles x 8 d-steps ----
      f32x16 accS0 = {}, accS1 = {};
      const char* Kb = Kbase + cur * 16384 + l31 * 256;
      __builtin_amdgcn_s_setprio(1);
#pragma unroll
      for (int dk = 0; dk < 8; dk++) {
        int sl = ((2 * dk + hi) ^ r7) * 16;
        short8 k0 = *(const short8*)(Kb + sl);
        short8 k1 = *(const short8*)(Kb + 32 * 256 + sl);
        accS0 = __builtin_amdgcn_mfma_f32_32x32x16_bf16(k0, qf[dk], accS0, 0, 0, 0);
        accS1 = __builtin_amdgcn_mfma_f32_32x32x16_bf16(k1, qf[dk], accS1, 0, 0, 0);
      }
      __builtin_amdgcn_s_setprio(0);

      // ---- scale + causal mask; lane holds P[q_row][kv], kv = 64t+(r&3)+8(r>>2)+4hi ----
      float p[32];
      const bool need_mask = (t * 64 + 63) > (qt * 128 + wq * 32);
      if (need_mask) {
#pragma unroll
        for (int r = 0; r < 16; r++) {
          int kv0 = t * 64 + (r & 3) + 8 * (r >> 2) + 4 * hi;
          p[r]      = (kv0      > q_row) ? -1e30f : accS0[r] * SCL2E;
          p[16 + r] = (kv0 + 32 > q_row) ? -1e30f : accS1[r] * SCL2E;
        }
      } else {
#pragma unroll
        for (int r = 0; r < 16; r++) { p[r] = accS0[r] * SCL2E; p[16 + r] = accS1[r] * SCL2E; }
      }

      // ---- row max: in-register tree + one cross-half permlane ----
      float t16[16];
#pragma unroll
      for (int i = 0; i < 16; i++) t16[i] = fmaxf(p[i], p[i + 16]);
#pragma unroll
      for (int st = 8; st >= 1; st >>= 1)
#pragma unroll
        for (int i = 0; i < st; i++) t16[i] = fmaxf(t16[i], t16[i + st]);
      int2v mr_ = plswap(__float_as_int(t16[0]), __float_as_int(t16[0]));
      float mx = fmaxf(t16[0], __int_as_float(hi ? mr_.x : mr_.y));

      // ---- defer-max (T13): rescale only when max grows past THR ----
      if (__any(mx > m_r + 8.0f)) {
        float mn = fmaxf(m_r, mx);
        float alpha = exp2f(m_r - mn);
        m_r = mn; l_r *= alpha;
#pragma unroll
        for (int dt = 0; dt < 4; dt++)
#pragma unroll
          for (int r = 0; r < 16; r++) accO[dt][r] *= alpha;
      }

      // ---- exp + row sum ----
#pragma unroll
      for (int i = 0; i < 32; i++) p[i] = exp2f(p[i] - m_r);
      float s16[16];
#pragma unroll
      for (int i = 0; i < 16; i++) s16[i] = p[i] + p[i + 16];
#pragma unroll
      for (int st = 8; st >= 1; st >>= 1)
#pragma unroll
        for (int i = 0; i < st; i++) s16[i] += s16[i + st];
      int2v sr_ = plswap(__float_as_int(s16[0]), __float_as_int(s16[0]));
      l_r += s16[0] + __int_as_float(hi ? sr_.x : sr_.y);

      // ---- pack P to bf16 pairs: pk[octet][c] = (kv=8o+4hi+2c, +1) ----
      unsigned pk[8][2];
#pragma unroll
      for (int o = 0; o < 8; o++)
#pragma unroll
        for (int c = 0; c < 2; c++) {
          float lo = p[(o >> 2) * 16 + (o & 3) * 4 + 2 * c];
          float hi_ = p[(o >> 2) * 16 + (o & 3) * 4 + 2 * c + 1];
          asm("v_cvt_pk_bf16_f32 %0, %1, %2" : "=v"(pk[o][c]) : "v"(lo), "v"(hi_));
        }

      // ---- PV: O^T += V^T P^T ; B-frag(ks) via permlane32_swap (VALU, dual-output) ----
      const char* Vb = Vbase + cur * 16384 + l31 * 128;
#pragma unroll
      for (int ks = 0; ks < 4; ks++) {
        int2v s0 = plswap((int)pk[2 * ks][0], (int)pk[2 * ks + 1][0]);
        int2v s1 = plswap((int)pk[2 * ks][1], (int)pk[2 * ks + 1][1]);
        uint4v pw;
        pw.x = (unsigned)s0.x;   // kv 16ks+8hi+{0,1}
        pw.y = (unsigned)s1.x;   // +{2,3}
        pw.z = (unsigned)s0.y;   // +{4,5}
        pw.w = (unsigned)s1.y;   // +{6,7}
        short8 pb = __builtin_bit_cast(short8, pw);
        int sl = ((2 * ks + hi) ^ r7) * 16;
        __builtin_amdgcn_s_setprio(1);
#pragma unroll
        for (int dt = 0; dt < 4; dt++) {
          short8 vf = *(const short8*)(Vb + dt * 32 * 128 + sl);
          accO[dt] = __builtin_amdgcn_mfma_f32_32x32x16_bf16(vf, pb, accO[dt], 0, 0, 0);
        }
        __builtin_amdgcn_s_setprio(0);
      }
    }

    // ---- combine even/odd partials, even group writes output ----
    __syncthreads();                                  // all compute done (cross-group)
    float* SM_acc = (float*)(SMEM + 65536);           // odd group's staging (dead now)
    float* SM_ml  = (float*)SMEM;                     // even group's staging (dead now)
    const int q_local = wq * 32 + l31;
    if (g == 1) {
#pragma unroll
      for (int dt = 0; dt < 4; dt++)
#pragma unroll
        for (int r = 0; r < 16; r++) {
          int d = 32 * dt + (r & 3) + 8 * (r >> 2) + 4 * hi;
          SM_acc[q_local * 128 + (d ^ l31)] = accO[dt][r];   // word-swz: conflict-free
        }
      if (hi == 0) { SM_ml[q_local * 2] = m_r; SM_ml[q_local * 2 + 1] = l_r; }
    }
    __syncthreads();                                  // partials visible
    if (g == 0) {
      float mo = SM_ml[q_local * 2], lo = SM_ml[q_local * 2 + 1];
      float m  = fmaxf(m_r, mo);
      float se = exp2f(m_r - m), so = exp2f(mo - m);
      float inv = 1.0f / (l_r * se + lo * so);
#pragma unroll
      for (int dt = 0; dt < 4; dt++)
#pragma unroll
        for (int q4 = 0; q4 < 4; q4++) {
          int dbase = 32 * dt + 8 * q4 + 4 * hi;
          u16x4 o;
#pragma unroll
          for (int j = 0; j < 4; j++) {
            int r = q4 * 4 + j, d = dbase + j;
            float vo = SM_acc[q_local * 128 + (d ^ l31)];
            o[j] = f2bf((accO[dt][r] * se + vo * so) * inv);
          }
          *(u16x4*)(ao + (size_t)q_row * HDIM + h * HD + dbase) = o;
        }
    }
  }
}

// ---------------- launch ----------------
extern "C" void kernel_launch(void* const* d_in, const int* in_sizes, int n_in,
                              void* d_out, int out_size, void* d_ws, size_t ws_size,
                              hipStream_t stream) {
  const float* x      = (const float*)d_in[0];
  const float* ve     = (const float*)d_in[1];
  const float* lam    = (const float*)d_in[2];
  const float* qkv_w  = (const float*)d_in[3];
  const float* proj_w = (const float*)d_in[4];
  float* out = (float*)d_out;

  char* p = (char*)d_ws;
  float* cosT = (float*)p;            p += (size_t)T_SEQ * 64 * 4;
  float* sinT = (float*)p;            p += (size_t)T_SEQ * 64 * 4;
  unsigned short* xb   = (unsigned short*)p; p += (size_t)T_SEQ * DIM * 2;
  unsigned short* wqb  = (unsigned short*)p; p += (size_t)3 * HDIM * DIM * 2;
  unsigned short* pwb  = (unsigned short*)p; p += (size_t)DIM * HDIM * 2;
  unsigned short* qkvb = (unsigned short*)p; p += (size_t)3 * NH * T_SEQ * HD * 2;
  unsigned short* vtb  = (unsigned short*)p; p += (size_t)NH * HD * T_SEQ * 2;
  unsigned short* aob  = (unsigned short*)p; p += (size_t)T_SEQ * HDIM * 2;

  cvt_f32_bf16<<<(T_SEQ * DIM / 4 + 255) / 256, 256, 0, stream>>>(x, xb, T_SEQ * DIM / 4);
  cvt_f32_bf16<<<(3 * HDIM * DIM / 4 + 255) / 256, 256, 0, stream>>>(qkv_w, wqb, 3 * HDIM * DIM / 4);
  cvt_f32_bf16<<<(DIM * HDIM / 4 + 255) / 256, 256, 0, stream>>>(proj_w, pwb, DIM * HDIM / 4);
  rope_tables<<<(T_SEQ * 64 + 255) / 256, 256, 0, stream>>>(cosT, sinT);

  gemm_bt<0><<<dim3(T_SEQ / 128, 3 * HDIM / 128), 256, 0, stream>>>(xb, wqb, DIM, qkvb, nullptr, 3 * HDIM);
  norm_rope<<<2 * NH * T_SEQ / 4, 256, 0, stream>>>(qkvb, cosT, sinT);
  vmix_transpose<<<dim3(T_SEQ / 64, HD / 64, NH), 256, 0, stream>>>(
      qkvb + (size_t)2 * NH * T_SEQ * HD, ve, lam, vtb);
  attn_fwd<<<256, 512, 0, stream>>>(qkvb, qkvb + (size_t)NH * T_SEQ * HD, vtb, aob);
  gemm_bt<1><<<dim3(T_SEQ / 128, HDIM / 128), 256, 0, stream>>>(aob, pwb, HDIM, nullptr, out, HDIM);
}

// Round 7
// 346.868 us; speedup vs baseline: 2.4949x; 1.1044x over previous
//
#include <hip/hip_runtime.h>
#include <cstdint>
#include <cstddef>

// ---------------- constants ----------------
constexpr int T_SEQ = 4096;
constexpr int NH    = 16;
constexpr int HD    = 128;
constexpr int DIM   = 2048;
constexpr int HDIM  = 2048;   // NH*HD

typedef __attribute__((ext_vector_type(8)))  short  short8;
typedef __attribute__((ext_vector_type(4)))  float  f32x4;
typedef __attribute__((ext_vector_type(16))) float  f32x16;
typedef __attribute__((ext_vector_type(8)))  unsigned short u16x8;
typedef __attribute__((ext_vector_type(4)))  unsigned short u16x4;
typedef __attribute__((ext_vector_type(4)))  unsigned uint4v;
typedef __attribute__((ext_vector_type(2)))  int int2v;

__device__ __forceinline__ unsigned short f2bf(float f) {
  unsigned u = __float_as_uint(f);
  return (unsigned short)((u + 0x7FFFu + ((u >> 16) & 1u)) >> 16);  // RNE
}
__device__ __forceinline__ float bf2f(unsigned short h) {
  return __uint_as_float(((unsigned)h) << 16);
}
__device__ __forceinline__ void gload_lds16(const void* g, void* l) {
  __builtin_amdgcn_global_load_lds((const __attribute__((address_space(1))) void*)g,
                                   (__attribute__((address_space(3))) void*)l, 16, 0, 0);
}
__device__ __forceinline__ int2v plswap(int a, int b) {
  return __builtin_amdgcn_permlane32_swap(a, b, false, false);
}
__device__ __forceinline__ void bar() {           // raw barrier: no implicit vmcnt(0)
  asm volatile("" ::: "memory");
  __builtin_amdgcn_s_barrier();
  asm volatile("" ::: "memory");
}
#define VMCNT(n) asm volatile("s_waitcnt vmcnt(" #n ")" ::: "memory")

// ---------------- fp32 -> bf16 convert ----------------
__global__ __launch_bounds__(256) void cvt_f32_bf16(const float* __restrict__ in,
                                                    unsigned short* __restrict__ out, int n4) {
  int i = blockIdx.x * 256 + threadIdx.x;
  if (i < n4) {
    float4 v = ((const float4*)in)[i];
    u16x4 o; o.x = f2bf(v.x); o.y = f2bf(v.y); o.z = f2bf(v.z); o.w = f2bf(v.w);
    ((u16x4*)out)[i] = o;
  }
}

// ---------------- RoPE tables ----------------
__global__ __launch_bounds__(256) void rope_tables(float* __restrict__ cosT, float* __restrict__ sinT) {
  int idx = blockIdx.x * 256 + threadIdx.x;           // T_SEQ*64
  if (idx >= T_SEQ * 64) return;
  int t = idx >> 6, i = idx & 63;
  float ang = (i < 32) ? exp2f(-10.0f * (float)i / 31.0f) : 0.0f;  // (1/1024)^(i/31)
  float th = (float)t * ang;
  cosT[idx] = cosf(th);
  sinT[idx] = sinf(th);
}

// ---------------- GEMM: C = A * B^T  (A:[M][K] bf16, B:[N][K] bf16) ----------------
// Deep-pipelined T2+T3+T4+T5 structure: BM=128, BN=256, BK=64, 512 threads (8 waves,
// 2M x 4N, per-wave 64x64). Triple-buffered LDS (3 x 48KB): stage tile t+2 while
// computing tile t -> one counted vmcnt(6) per K-tile, never 0 in the main loop.
// 2 phases per tile (kk-split), each {8 ds_read_b128 | 3 gload_lds | barrier |
// 16 MFMA (setprio) | barrier}. Raw s_barrier (NOT __syncthreads: implicit vmcnt(0)
// would drain the pipeline). LDS XOR swizzle slot^=(row&7) on both tiles, staged via
// pre-swizzled global source (both-sides-or-neither, rule #21).
// M is fixed at 4096 (32 m-blocks); grid = 32*Nblk, column-major, XCD-swizzled.
// MODE 0: write bf16 into qkv layout [c][h][t][d]; MODE 1: write fp32 [t][n].
template <int MODE>
__global__ __launch_bounds__(512) void gemm256(const unsigned short* __restrict__ A,
                                               const unsigned short* __restrict__ B,
                                               int K, unsigned short* __restrict__ outb,
                                               float* __restrict__ outf, int N) {
  __shared__ __align__(16) char SM[3 * 49152];   // 144KB: 3 x [A 16KB | B 32KB]
  const int tid = threadIdx.x, w = tid >> 6, lane = tid & 63;
  const int wm = w >> 2, wn = w & 3;
  const int lr = lane >> 4, lc = lane & 15, lc7 = lc & 7;
  // XCD-aware bijective swizzle (grid % 8 == 0), column-major (m fastest):
  const int cpx = gridDim.x >> 3;
  const int idx = (blockIdx.x & 7) * cpx + (blockIdx.x >> 3);
  const int m0 = (idx & 31) * 128, n0 = (idx >> 5) * 256;

  const int arow = lane >> 3;                           // row within 8-row chunk
  const int xcol = ((lane & 7) ^ ((lane >> 3) & 7)) * 8;  // pre-swizzled source col

  auto stageA = [&](int buf, int t) {                   // 2 chunks: rows 0..127
    char* base = SM + buf * 49152;
#pragma unroll
    for (int i = 0; i < 2; i++) {
      int c = w + i * 8;
      gload_lds16(A + (size_t)(m0 + c * 8 + arow) * K + t * 64 + xcol, base + c * 1024);
    }
  };
  auto stageB0 = [&](int buf, int t) {                  // chunk w: rows of B-panel
    char* base = SM + buf * 49152 + 16384;
    gload_lds16(B + (size_t)(n0 + w * 8 + arow) * K + t * 64 + xcol, base + w * 1024);
  };
  auto stageB1 = [&](int buf, int t) {                  // chunks w+8, w+16, w+24
    char* base = SM + buf * 49152 + 16384;
#pragma unroll
    for (int i = 1; i < 4; i++) {
      int c = w + i * 8;
      gload_lds16(B + (size_t)(n0 + c * 8 + arow) * K + t * 64 + xcol, base + c * 1024);
    }
  };

  f32x4 acc[4][4] = {};
  const int NT = K >> 6;

  // prologue: stage tiles 0 and 1 (6 loads each), confirm tile 0
  stageA(0, 0); stageB0(0, 0); stageB1(0, 0);
  stageA(1, 1); stageB0(1, 1); stageB1(1, 1);
  VMCNT(6);
  bar();

#pragma unroll 1
  for (int t = 0; t < NT; t++) {
    const int c = t % 3, s = (t + 2) % 3;
    const bool st = (t + 2) < NT;
    const char* Ab = SM + c * 49152;
    const char* Bb = Ab + 16384;

    // ---- phase 0 (kk = 0) ----
    short8 a[4], b[4];
#pragma unroll
    for (int mi = 0; mi < 4; mi++)
      a[mi] = *(const short8*)(Ab + (wm * 64 + mi * 16 + lc) * 128 + ((0 + lr) ^ lc7) * 16);
#pragma unroll
    for (int ni = 0; ni < 4; ni++)
      b[ni] = *(const short8*)(Bb + (wn * 64 + ni * 16 + lc) * 128 + ((0 + lr) ^ lc7) * 16);
    if (st) { stageA(s, t + 2); stageB0(s, t + 2); }
    bar();
    __builtin_amdgcn_s_setprio(1);
#pragma unroll
    for (int mi = 0; mi < 4; mi++)
#pragma unroll
      for (int ni = 0; ni < 4; ni++)
        acc[mi][ni] = __builtin_amdgcn_mfma_f32_16x16x32_bf16(a[mi], b[ni], acc[mi][ni], 0, 0, 0);
    __builtin_amdgcn_s_setprio(0);
    bar();

    // ---- phase 1 (kk = 1) ----
#pragma unroll
    for (int mi = 0; mi < 4; mi++)
      a[mi] = *(const short8*)(Ab + (wm * 64 + mi * 16 + lc) * 128 + ((4 + lr) ^ lc7) * 16);
#pragma unroll
    for (int ni = 0; ni < 4; ni++)
      b[ni] = *(const short8*)(Bb + (wn * 64 + ni * 16 + lc) * 128 + ((4 + lr) ^ lc7) * 16);
    if (st) stageB1(s, t + 2);
    if (st) { VMCNT(6); } else { VMCNT(0); }   // confirm tile t+1 (tail: drain)
    bar();
    __builtin_amdgcn_s_setprio(1);
#pragma unroll
    for (int mi = 0; mi < 4; mi++)
#pragma unroll
      for (int ni = 0; ni < 4; ni++)
        acc[mi][ni] = __builtin_amdgcn_mfma_f32_16x16x32_bf16(a[mi], b[ni], acc[mi][ni], 0, 0, 0);
    __builtin_amdgcn_s_setprio(0);
    bar();
  }

  // ---- epilogue ----
#pragma unroll
  for (int mi = 0; mi < 4; mi++)
#pragma unroll
    for (int ni = 0; ni < 4; ni++)
#pragma unroll
      for (int r = 0; r < 4; r++) {
        int t = m0 + wm * 64 + mi * 16 + lr * 4 + r;
        int n = n0 + wn * 64 + ni * 16 + lc;
        float v = acc[mi][ni][r];
        if (MODE == 0) {
          int cc = n >> 11, e = n & 2047, h = e >> 7, d = e & 127;
          outb[(((size_t)cc * NH + h) * T_SEQ + t) * HD + d] = f2bf(v);
        } else {
          outf[(size_t)t * N + n] = v;
        }
      }
}

// ---------------- RMSNorm + RoPE (in-place on q,k; layout [c][h][t][d]) ----------------
__global__ __launch_bounds__(256) void norm_rope(unsigned short* __restrict__ qkvb,
                                                 const float* __restrict__ cosT,
                                                 const float* __restrict__ sinT) {
  int r = blockIdx.x * 4 + (threadIdx.x >> 6);   // row over [c][h][t], c in {0,1}
  int lane = threadIdx.x & 63;
  int t = r % T_SEQ;
  unsigned short* row = qkvb + (size_t)r * HD;
  float f1 = bf2f(row[lane]), f2 = bf2f(row[lane + 64]);
  float ss = f1 * f1 + f2 * f2;
#pragma unroll
  for (int off = 32; off; off >>= 1) ss += __shfl_xor(ss, off, 64);
  float rs = rsqrtf(ss * (1.0f / 128.0f) + 1e-6f);
  f1 *= rs; f2 *= rs;
  float c_ = cosT[t * 64 + lane], s_ = sinT[t * 64 + lane];
  row[lane]      = f2bf(f1 * c_ + f2 * s_);
  row[lane + 64] = f2bf(-f1 * s_ + f2 * c_);
}

// ---------------- v' = l0*v + l1*ve, transposed to v_t[h][d][t] ----------------
__global__ __launch_bounds__(256) void vmix_transpose(const unsigned short* __restrict__ vb,
                                                      const float* __restrict__ ve,
                                                      const float* __restrict__ lam,
                                                      unsigned short* __restrict__ vt) {
  __shared__ float tile[64][65];
  const int h = blockIdx.z, t0 = blockIdx.x * 64, d0 = blockIdx.y * 64;
  const float l0 = lam[0], l1 = lam[1];
  const int tid = threadIdx.x;
  const int tl = tid >> 4, dl4 = (tid & 15) * 4;
#pragma unroll
  for (int i = 0; i < 4; i++) {
    int t_local = tl + i * 16;
    int t = t0 + t_local;
    const unsigned short* vp = vb + ((size_t)h * T_SEQ + t) * HD + d0 + dl4;
    const float* vep = ve + (size_t)t * HDIM + h * HD + d0 + dl4;
    u16x4 vv = *(const u16x4*)vp;
    float4 vef = *(const float4*)vep;
    tile[t_local][dl4 + 0] = l0 * bf2f(vv.x) + l1 * vef.x;
    tile[t_local][dl4 + 1] = l0 * bf2f(vv.y) + l1 * vef.y;
    tile[t_local][dl4 + 2] = l0 * bf2f(vv.z) + l1 * vef.z;
    tile[t_local][dl4 + 3] = l0 * bf2f(vv.w) + l1 * vef.w;
  }
  __syncthreads();
#pragma unroll
  for (int i = 0; i < 2; i++) {
    int idx = tid + i * 256;
    int d_local = idx >> 3, tloc = (idx & 7) * 8;
    u16x8 o;
#pragma unroll
    for (int j = 0; j < 8; j++) o[j] = f2bf(tile[tloc + j][d_local]);
    *(u16x8*)(vt + ((size_t)h * HD + d0 + d_local) * T_SEQ + t0 + tloc) = o;
  }
}

// ---------------- flash attention (causal), swapped-operand 32x32x16 ----------------
// 8 warps / 512 threads; kv-parity split (warps 0-3 even tiles, 4-7 odd) with LDS merge.
// Group-local monotonic LDS-counter barrier per iter -> the two parity groups drift
// phase (VALU of one overlaps MFMA+LDS of the other). Full block barriers only at
// q-tile start and the cross-group combine.
__global__ __launch_bounds__(512)
__attribute__((amdgpu_waves_per_eu(2, 2)))
void attn_fwd(const unsigned short* __restrict__ qb,
              const unsigned short* __restrict__ kb,
              const unsigned short* __restrict__ vt,
              unsigned short* __restrict__ ao) {
  __shared__ __align__(16) char SMEM[131072];   // [group][ K 2x16KB | V 2x16KB ]
  __shared__ int gctr[2];                       // group-barrier monotonic counters
  const int bid = blockIdx.x;
  const int h  = (bid & 7) + ((bid >> 7) << 3);  // XCD swizzle: head h on XCD h%8
  const int pr = (bid >> 3) & 15;
  const int tid = threadIdx.x, w = tid >> 6, lane = tid & 63;
  const int g = w >> 2, wq = w & 3;
  const int l31 = lane & 31, hi = lane >> 5, r7 = l31 & 7;
  const unsigned short* qh = qb + (size_t)h * T_SEQ * HD;
  const unsigned short* kh = kb + (size_t)h * T_SEQ * HD;
  const unsigned short* vh = vt + (size_t)h * HD * T_SEQ;

  if (tid < 2) gctr[tid] = 0;
  __syncthreads();
  int bcnt = 0;
  auto GBAR = [&]() {   // group-local barrier: 4 waves of group g
    asm volatile("s_waitcnt lgkmcnt(0)" ::: "memory");
    ++bcnt;
    if (lane == 0)
      __hip_atomic_fetch_add(&gctr[g], 1, __ATOMIC_RELEASE, __HIP_MEMORY_SCOPE_WORKGROUP);
    while (__hip_atomic_load(&gctr[g], __ATOMIC_ACQUIRE, __HIP_MEMORY_SCOPE_WORKGROUP) < 4 * bcnt)
      __builtin_amdgcn_s_sleep(1);
  };

  char* Kbase = SMEM + g * 65536;
  char* Vbase = SMEM + g * 65536 + 32768;

  const int kcrow = lane >> 4, kcol16 = lane & 15;   // K staging: 4 rows / 1KB chunk
  const int vcrow = lane >> 3, vslot0 = lane & 7;    // V staging: 8 rows / 1KB chunk

  auto STAGE = [&](int buf, int t) {                 // t = global kv tile index
#pragma unroll
    for (int i = 0; i < 4; i++) {
      int krow = (wq * 4 + i) * 4 + kcrow;
      int kcol = (kcol16 ^ (krow & 7)) * 8;          // pre-swizzled source (rule #21)
      gload_lds16(kh + (size_t)(t * 64 + krow) * HD + kcol,
                  Kbase + buf * 16384 + (wq * 4 + i) * 1024);
      int vrow = (wq * 4 + i) * 8 + vcrow;
      int vcol = (vslot0 ^ (vrow & 7)) * 8;
      gload_lds16(vh + (size_t)vrow * T_SEQ + t * 64 + vcol,
                  Vbase + buf * 16384 + (wq * 4 + i) * 1024);
    }
  };

  const float SCL2E = 0.088388347648318447f * 1.44269504f;  // 1/sqrt(128) * log2(e)

#pragma unroll 1
  for (int which = 0; which < 2; ++which) {
    const int qt = which ? pr : (31 - pr);     // heavy tile first
    const int ng = qt + 1;                     // tiles for THIS group (parity g)
    const int q_row = qt * 128 + wq * 32 + l31;

    short8 qf[8];                              // B-frag: Q[q_row][16dk + 8hi + 0..7]
#pragma unroll
    for (int dk = 0; dk < 8; dk++)
      qf[dk] = *(const short8*)(qh + (size_t)q_row * HD + dk * 16 + hi * 8);

    f32x16 accO[4] = {};                       // O^T: col=q, rows d (4 tiles of 32)
    float m_r = -1e30f, l_r = 0.0f;

    __syncthreads();                           // prev combine reads done (cross-group)
    STAGE(0, g);

#pragma unroll 1
    for (int it = 0; it < ng; it++) {
      const int t = 2 * it + g;                // this group's kv tile
      const int cur = it & 1;
      asm volatile("s_waitcnt vmcnt(0)" ::: "memory");  // own stage(cur) landed
      GBAR();                                           // group's stage(cur) landed
      if (it + 1 < ng) STAGE(cur ^ 1, t + 2);           // prefetch under compute

      // ---- S^T = K Q^T : 2 kv-subtiles x 8 d-steps ----
      f32x16 accS0 = {}, accS1 = {};
      const char* Kb = Kbase + cur * 16384 + l31 * 256;
      __builtin_amdgcn_s_setprio(1);
#pragma unroll
      for (int dk = 0; dk < 8; dk++) {
        int sl = ((2 * dk + hi) ^ r7) * 16;
        short8 k0 = *(const short8*)(Kb + sl);
        short8 k1 = *(const short8*)(Kb + 32 * 256 + sl);
        accS0 = __builtin_amdgcn_mfma_f32_32x32x16_bf16(k0, qf[dk], accS0, 0, 0, 0);
        accS1 = __builtin_amdgcn_mfma_f32_32x32x16_bf16(k1, qf[dk], accS1, 0, 0, 0);
      }
      __builtin_amdgcn_s_setprio(0);

      // ---- scale + causal mask; lane holds P[q_row][kv], kv = 64t+(r&3)+8(r>>2)+4hi ----
      float p[32];
      const bool need_mask = (t * 64 + 63) > (qt * 128 + wq * 32);
      if (need_mask) {
#pragma unroll
        for (int r = 0; r < 16; r++) {
          int kv0 = t * 64 + (r & 3) + 8 * (r >> 2) + 4 * hi;
          p[r]      = (kv0      > q_row) ? -1e30f : accS0[r] * SCL2E;
          p[16 + r] = (kv0 + 32 > q_row) ? -1e30f : accS1[r] * SCL2E;
        }
      } else {
#pragma unroll
        for (int r = 0; r < 16; r++) { p[r] = accS0[r] * SCL2E; p[16 + r] = accS1[r] * SCL2E; }
      }

      // ---- row max: in-register tree + one cross-half permlane ----
      float t16[16];
#pragma unroll
      for (int i = 0; i < 16; i++) t16[i] = fmaxf(p[i], p[i + 16]);
#pragma unroll
      for (int st = 8; st >= 1; st >>= 1)
#pragma unroll
        for (int i = 0; i < st; i++) t16[i] = fmaxf(t16[i], t16[i + st]);
      int2v mr_ = plswap(__float_as_int(t16[0]), __float_as_int(t16[0]));
      float mx = fmaxf(t16[0], __int_as_float(hi ? mr_.x : mr_.y));

      // ---- defer-max (T13): rescale only when max grows past THR ----
      if (__any(mx > m_r + 8.0f)) {
        float mn = fmaxf(m_r, mx);
        float alpha = exp2f(m_r - mn);
        m_r = mn; l_r *= alpha;
#pragma unroll
        for (int dt = 0; dt < 4; dt++)
#pragma unroll
          for (int r = 0; r < 16; r++) accO[dt][r] *= alpha;
      }

      // ---- exp + row sum ----
#pragma unroll
      for (int i = 0; i < 32; i++) p[i] = exp2f(p[i] - m_r);
      float s16[16];
#pragma unroll
      for (int i = 0; i < 16; i++) s16[i] = p[i] + p[i + 16];
#pragma unroll
      for (int st = 8; st >= 1; st >>= 1)
#pragma unroll
        for (int i = 0; i < st; i++) s16[i] += s16[i + st];
      int2v sr_ = plswap(__float_as_int(s16[0]), __float_as_int(s16[0]));
      l_r += s16[0] + __int_as_float(hi ? sr_.x : sr_.y);

      // ---- pack P to bf16 pairs: pk[octet][c] = (kv=8o+4hi+2c, +1) ----
      unsigned pk[8][2];
#pragma unroll
      for (int o = 0; o < 8; o++)
#pragma unroll
        for (int c = 0; c < 2; c++) {
          float lo = p[(o >> 2) * 16 + (o & 3) * 4 + 2 * c];
          float hi_ = p[(o >> 2) * 16 + (o & 3) * 4 + 2 * c + 1];
          asm("v_cvt_pk_bf16_f32 %0, %1, %2" : "=v"(pk[o][c]) : "v"(lo), "v"(hi_));
        }

      // ---- PV: O^T += V^T P^T ; B-frag(ks) via permlane32_swap (VALU, dual-output) ----
      const char* Vb = Vbase + cur * 16384 + l31 * 128;
#pragma unroll
      for (int ks = 0; ks < 4; ks++) {
        int2v s0 = plswap((int)pk[2 * ks][0], (int)pk[2 * ks + 1][0]);
        int2v s1 = plswap((int)pk[2 * ks][1], (int)pk[2 * ks + 1][1]);
        uint4v pw;
        pw.x = (unsigned)s0.x;   // kv 16ks+8hi+{0,1}
        pw.y = (unsigned)s1.x;   // +{2,3}
        pw.z = (unsigned)s0.y;   // +{4,5}
        pw.w = (unsigned)s1.y;   // +{6,7}
        short8 pb = __builtin_bit_cast(short8, pw);
        int sl = ((2 * ks + hi) ^ r7) * 16;
        __builtin_amdgcn_s_setprio(1);
#pragma unroll
        for (int dt = 0; dt < 4; dt++) {
          short8 vf = *(const short8*)(Vb + dt * 32 * 128 + sl);
          accO[dt] = __builtin_amdgcn_mfma_f32_32x32x16_bf16(vf, pb, accO[dt], 0, 0, 0);
        }
        __builtin_amdgcn_s_setprio(0);
      }
    }

    // ---- combine even/odd partials, even group writes output ----
    __syncthreads();                                  // all compute done (cross-group)
    float* SM_acc = (float*)(SMEM + 65536);           // odd group's staging (dead now)
    float* SM_ml  = (float*)SMEM;                     // even group's staging (dead now)
    const int q_local = wq * 32 + l31;
    if (g == 1) {
#pragma unroll
      for (int dt = 0; dt < 4; dt++)
#pragma unroll
        for (int r = 0; r < 16; r++) {
          int d = 32 * dt + (r & 3) + 8 * (r >> 2) + 4 * hi;
          SM_acc[q_local * 128 + (d ^ l31)] = accO[dt][r];   // word-swz: conflict-free
        }
      if (hi == 0) { SM_ml[q_local * 2] = m_r; SM_ml[q_local * 2 + 1] = l_r; }
    }
    __syncthreads();                                  // partials visible
    if (g == 0) {
      float mo = SM_ml[q_local * 2], lo = SM_ml[q_local * 2 + 1];
      float m  = fmaxf(m_r, mo);
      float se = exp2f(m_r - m), so = exp2f(mo - m);
      float inv = 1.0f / (l_r * se + lo * so);
#pragma unroll
      for (int dt = 0; dt < 4; dt++)
#pragma unroll
        for (int q4 = 0; q4 < 4; q4++) {
          int dbase = 32 * dt + 8 * q4 + 4 * hi;
          u16x4 o;
#pragma unroll
          for (int j = 0; j < 4; j++) {
            int r = q4 * 4 + j, d = dbase + j;
            float vo = SM_acc[q_local * 128 + (d ^ l31)];
            o[j] = f2bf((accO[dt][r] * se + vo * so) * inv);
          }
          *(u16x4*)(ao + (size_t)q_row * HDIM + h * HD + dbase) = o;
        }
    }
  }
}

// ---------------- launch ----------------
extern "C" void kernel_launch(void* const* d_in, const int* in_sizes, int n_in,
                              void* d_out, int out_size, void* d_ws, size_t ws_size,
                              hipStream_t stream) {
  const float* x      = (const float*)d_in[0];
  const float* ve     = (const float*)d_in[1];
  const float* lam    = (const float*)d_in[2];
  const float* qkv_w  = (const float*)d_in[3];
  const float* proj_w = (const float*)d_in[4];
  float* out = (float*)d_out;

  char* p = (char*)d_ws;
  float* cosT = (float*)p;            p += (size_t)T_SEQ * 64 * 4;
  float* sinT = (float*)p;            p += (size_t)T_SEQ * 64 * 4;
  unsigned short* xb   = (unsigned short*)p; p += (size_t)T_SEQ * DIM * 2;
  unsigned short* wqb  = (unsigned short*)p; p += (size_t)3 * HDIM * DIM * 2;
  unsigned short* pwb  = (unsigned short*)p; p += (size_t)DIM * HDIM * 2;
  unsigned short* qkvb = (unsigned short*)p; p += (size_t)3 * NH * T_SEQ * HD * 2;
  unsigned short* vtb  = (unsigned short*)p; p += (size_t)NH * HD * T_SEQ * 2;
  unsigned short* aob  = (unsigned short*)p; p += (size_t)T_SEQ * HDIM * 2;

  cvt_f32_bf16<<<(T_SEQ * DIM / 4 + 255) / 256, 256, 0, stream>>>(x, xb, T_SEQ * DIM / 4);
  cvt_f32_bf16<<<(3 * HDIM * DIM / 4 + 255) / 256, 256, 0, stream>>>(qkv_w, wqb, 3 * HDIM * DIM / 4);
  cvt_f32_bf16<<<(DIM * HDIM / 4 + 255) / 256, 256, 0, stream>>>(proj_w, pwb, DIM * HDIM / 4);
  rope_tables<<<(T_SEQ * 64 + 255) / 256, 256, 0, stream>>>(cosT, sinT);

  // QKV: M=4096 (32 m-blocks), N=6144 (24 n-blocks) -> 768 blocks = 3/CU exactly
  gemm256<0><<<768, 512, 0, stream>>>(xb, wqb, DIM, qkvb, nullptr, 3 * HDIM);
  norm_rope<<<2 * NH * T_SEQ / 4, 256, 0, stream>>>(qkvb, cosT, sinT);
  vmix_transpose<<<dim3(T_SEQ / 64, HD / 64, NH), 256, 0, stream>>>(
      qkvb + (size_t)2 * NH * T_SEQ * HD, ve, lam, vtb);
  attn_fwd<<<256, 512, 0, stream>>>(qkvb, qkvb + (size_t)NH * T_SEQ * HD, vtb, aob);
  // proj: M=4096 (32), N=2048 (8 n-blocks) -> 256 blocks = 1/CU exactly
  gemm256<1><<<256, 512, 0, stream>>>(aob, pwb, HDIM, nullptr, out, HDIM);
}